// Round 1
// baseline (2011.980 us; speedup 1.0000x reference)
//
#include <hip/hip_runtime.h>
#include <math.h>

#define NPIX 9216
#define NBATCH 8
#define NC 64
#define ND 129
#define NK 4
#define NCOMBO 64   // 2 branches * 8 batch * 4 k
#define PITCH 132   // row pitch for 129-wide matrices in global
#define APITCH 131  // LDS pitch for cholesky (odd-ish stride -> no bank conflict)

// ---------------- helpers ----------------

__device__ __forceinline__ const float* zrow(const float* fgbg, const float* cfcb, const float* qf,
                                             int br, int b, int d){
  if(d < NC)        return fgbg + ((size_t)((br*NBATCH + b)*NC + d))*NPIX;
  else if(d < 2*NC) return qf   + ((size_t)(b*NC + (d - NC)))*NPIX;
  else              return cfcb + (size_t)(br*NBATCH + b)*NPIX;
}

__device__ __forceinline__ float blockSum256(float v, float* rb){
  int tid = threadIdx.x;
  rb[tid] = v; __syncthreads();
  #pragma unroll
  for(int s = 128; s > 0; s >>= 1){
    if(tid < s) rb[tid] += rb[tid + s];
    __syncthreads();
  }
  float r = rb[0]; __syncthreads();
  return r;
}

// ---------------- stage 1: fg/bg/cosine ----------------

__global__ __launch_bounds__(256) void k_prep(const float* sf, const float* smk, const float* qf,
                                              float* fgbg, float* cfcb){
  int tid = threadIdx.x, b = blockIdx.y;
  int n = blockIdx.x*256 + tid;
  float m = smk[(size_t)b*NPIX + n];
  const float* S = sf + ((size_t)(b*NC))*NPIX + n;
  const float* Q = qf + ((size_t)(b*NC))*NPIX + n;
  float* FG = fgbg + ((size_t)(b*NC))*NPIX + n;
  float* BG = fgbg + ((size_t)((NBATCH + b)*NC))*NPIX + n;
  float df = 0.f, db = 0.f, nf = 0.f, nb_ = 0.f, nq = 0.f;
  #pragma unroll 4
  for(int c = 0; c < NC; c++){
    float s = S[(size_t)c*NPIX], q = Q[(size_t)c*NPIX];
    float f = s*m, g = s - f;
    FG[(size_t)c*NPIX] = f; BG[(size_t)c*NPIX] = g;
    df += f*q; db += g*q; nf += f*f; nb_ += g*g; nq += q*q;
  }
  float rq = fmaxf(sqrtf(nq), 1e-8f);
  cfcb[(size_t)b*NPIX + n]            = df / (fmaxf(sqrtf(nf),  1e-8f) * rq);
  cfcb[(size_t)(NBATCH + b)*NPIX + n] = db / (fmaxf(sqrtf(nb_), 1e-8f) * rq);
}

// ---------------- estimator ----------------

__global__ __launch_bounds__(256) void k_conv1(const float* fgbg, const float* cfcb, const float* qf,
                                               const float* w1, const float* b1, float* h1){
  __shared__ float Ws[ND*NC];
  __shared__ float B1[NC];
  int tid = threadIdx.x, b = blockIdx.y, br = blockIdx.z;
  for(int i = tid; i < ND*NC; i += 256) Ws[i] = w1[i];
  if(tid < NC) B1[tid] = b1[tid];
  __syncthreads();
  int n = blockIdx.x*256 + tid;
  float acc[NC];
  #pragma unroll
  for(int j = 0; j < NC; j++) acc[j] = B1[j];
  const float* Z0 = fgbg + ((size_t)((br*NBATCH + b)*NC))*NPIX + n;
  #pragma unroll 2
  for(int d = 0; d < NC; d++){
    float z = Z0[(size_t)d*NPIX];
    #pragma unroll
    for(int j = 0; j < NC; j++) acc[j] += z*Ws[d*NC + j];
  }
  const float* Q = qf + ((size_t)(b*NC))*NPIX + n;
  #pragma unroll 2
  for(int d = 0; d < NC; d++){
    float z = Q[(size_t)d*NPIX];
    #pragma unroll
    for(int j = 0; j < NC; j++) acc[j] += z*Ws[(NC + d)*NC + j];
  }
  {
    float z = cfcb[(size_t)(br*NBATCH + b)*NPIX + n];
    #pragma unroll
    for(int j = 0; j < NC; j++) acc[j] += z*Ws[128*NC + j];
  }
  float* O = h1 + ((size_t)((br*NBATCH + b)*NC))*NPIX + n;
  #pragma unroll
  for(int j = 0; j < NC; j++) O[(size_t)j*NPIX] = acc[j];
}

__global__ __launch_bounds__(256) void k_bnstats(const float* x, float* meanv, float* rstdv, int C){
  __shared__ float rb[256];
  int c = blockIdx.x, br = blockIdx.y, tid = threadIdx.x;
  float s = 0.f, ss = 0.f;
  for(int b = 0; b < NBATCH; b++){
    const float* X = x + ((size_t)((br*NBATCH + b)*C + c))*NPIX;
    for(int n = tid; n < NPIX; n += 256){ float v = X[n]; s += v; ss += v*v; }
  }
  float S  = blockSum256(s,  rb);
  float SS = blockSum256(ss, rb);
  if(tid == 0){
    float m   = S  / (float)(NBATCH*NPIX);
    float var = SS / (float)(NBATCH*NPIX) - m*m;
    meanv[br*C + c] = m;
    rstdv[br*C + c] = 1.0f / sqrtf(var + 1e-5f);
  }
}

__global__ __launch_bounds__(256) void k_conv2(const float* h1, const float* mean1, const float* rstd1,
                                               const float* g1, const float* be1,
                                               const float* w2, const float* b2, float* h2){
  __shared__ float Ws[NC*16];
  __shared__ float Pm[NC], Pr[NC], Pg[NC], Pb[NC];
  __shared__ float B2[16];
  int tid = threadIdx.x, b = blockIdx.y, br = blockIdx.z;
  for(int i = tid; i < NC*16; i += 256) Ws[i] = w2[i];
  if(tid < NC){ Pm[tid] = mean1[br*NC + tid]; Pr[tid] = rstd1[br*NC + tid]; Pg[tid] = g1[tid]; Pb[tid] = be1[tid]; }
  if(tid < 16) B2[tid] = b2[tid];
  __syncthreads();
  int n = blockIdx.x*256 + tid;
  const float* X = h1 + ((size_t)((br*NBATCH + b)*NC))*NPIX + n;
  float acc[16];
  #pragma unroll
  for(int j = 0; j < 16; j++) acc[j] = B2[j];
  for(int c = 0; c < NC; c++){
    float v = (X[(size_t)c*NPIX] - Pm[c])*Pr[c]*Pg[c] + Pb[c];
    v = fmaxf(v, 0.f);
    #pragma unroll
    for(int j = 0; j < 16; j++) acc[j] += v*Ws[c*16 + j];
  }
  float* O = h2 + ((size_t)((br*NBATCH + b)*16))*NPIX + n;
  #pragma unroll
  for(int j = 0; j < 16; j++) O[(size_t)j*NPIX] = acc[j];
}

__global__ __launch_bounds__(256) void k_gamma(const float* h2, const float* mean2, const float* rstd2,
                                               const float* g2, const float* be2,
                                               const float* w3, const float* b3,
                                               float* gamma, float* sumg){
  __shared__ float W3[16*4];
  __shared__ float Pm[16], Pr[16], Pg[16], Pb[16];
  __shared__ float B3[4];
  __shared__ float rb[256];
  int tid = threadIdx.x, b = blockIdx.y, br = blockIdx.z;
  if(tid < 64) W3[tid] = w3[tid];
  if(tid < 4)  B3[tid] = b3[tid];
  if(tid < 16){ Pm[tid] = mean2[br*16 + tid]; Pr[tid] = rstd2[br*16 + tid]; Pg[tid] = g2[tid]; Pb[tid] = be2[tid]; }
  __syncthreads();
  int n = blockIdx.x*256 + tid;
  const float* X = h2 + ((size_t)((br*NBATCH + b)*16))*NPIX + n;
  float l0 = B3[0], l1 = B3[1], l2 = B3[2], l3 = B3[3];
  #pragma unroll
  for(int c = 0; c < 16; c++){
    float v = (X[(size_t)c*NPIX] - Pm[c])*Pr[c]*Pg[c] + Pb[c];
    v = fmaxf(v, 0.f);
    l0 += v*W3[c*4 + 0]; l1 += v*W3[c*4 + 1]; l2 += v*W3[c*4 + 2]; l3 += v*W3[c*4 + 3];
  }
  float mx = fmaxf(fmaxf(l0, l1), fmaxf(l2, l3));
  float e0 = expf(l0 - mx), e1 = expf(l1 - mx), e2 = expf(l2 - mx), e3 = expf(l3 - mx);
  float inv = 1.0f / (e0 + e1 + e2 + e3);
  float q0 = e0*inv, q1 = e1*inv, q2 = e2*inv, q3 = e3*inv;
  float* G = gamma + ((size_t)((br*NBATCH + b)*NK))*NPIX + n;
  G[0] = q0; G[NPIX] = q1; G[2*NPIX] = q2; G[3*NPIX] = q3;
  int cb = br*NBATCH + b;
  float t;
  t = blockSum256(q0, rb); if(tid == 0) atomicAdd(&sumg[cb*4 + 0], t);
  t = blockSum256(q1, rb); if(tid == 0) atomicAdd(&sumg[cb*4 + 1], t);
  t = blockSum256(q2, rb); if(tid == 0) atomicAdd(&sumg[cb*4 + 2], t);
  t = blockSum256(q3, rb); if(tid == 0) atomicAdd(&sumg[cb*4 + 3], t);
}

// ---------------- GMM: mu ----------------

__global__ __launch_bounds__(256) void k_musum(const float* fgbg, const float* cfcb, const float* qf,
                                               const float* gamma, float* musum){
  __shared__ float rb[256];
  int d = blockIdx.x, b = blockIdx.y, br = blockIdx.z, tid = threadIdx.x;
  const float* Z = zrow(fgbg, cfcb, qf, br, b, d);
  const float* G = gamma + ((size_t)((br*NBATCH + b)*NK))*NPIX;
  float a0 = 0.f, a1 = 0.f, a2 = 0.f, a3 = 0.f;
  for(int n = tid; n < NPIX; n += 256){
    float z = Z[n];
    a0 += G[n]*z; a1 += G[NPIX + n]*z; a2 += G[2*NPIX + n]*z; a3 += G[3*NPIX + n]*z;
  }
  int cb = br*NBATCH + b;
  float t;
  t = blockSum256(a0, rb); if(tid == 0) musum[((size_t)(cb*4 + 0))*ND + d] = t;
  t = blockSum256(a1, rb); if(tid == 0) musum[((size_t)(cb*4 + 1))*ND + d] = t;
  t = blockSum256(a2, rb); if(tid == 0) musum[((size_t)(cb*4 + 2))*ND + d] = t;
  t = blockSum256(a3, rb); if(tid == 0) musum[((size_t)(cb*4 + 3))*ND + d] = t;
}

__global__ __launch_bounds__(256) void k_phimufin(const float* sumg, float* phi, float* logphi, float* mu){
  int tid = threadIdx.x;
  if(tid < NCOMBO){
    float sg = sumg[tid];
    float p = sg / (float)NPIX;
    phi[tid] = p;
    logphi[tid] = logf(p + 1e-12f);
  }
  for(int i = tid; i < NCOMBO*ND; i += 256){
    int c = i / ND;
    mu[i] = mu[i] / sumg[c];
  }
}

// ---------------- GMM: weighted second moment (upper triangle, tiles of 32) ----------------
// slots per (seg,cb): k=0,1,2 weighted; k=3 holds UNWEIGHTED total (M3 = tot - M0 - M1 - M2, since sum_k gamma = 1)

__global__ __launch_bounds__(256) void k_cov(const float* fgbg, const float* cfcb, const float* qf,
                                             const float* gamma, float* Mpart){
  __shared__ float SD[32][34];
  __shared__ float SE[32][34];
  __shared__ __align__(16) float SG[32][4];
  int p = blockIdx.x, cbi = blockIdx.y, seg = blockIdx.z;
  int ti, tj;
  if(p < 4){ ti = 0; tj = p; } else if(p < 7){ ti = 1; tj = p - 3; }
  else if(p < 9){ ti = 2; tj = p - 5; } else { ti = 3; tj = 3; }
  int br = cbi >> 3, b = cbi & 7;
  int d0 = ti*32, e0 = tj*32;
  int tid = threadIdx.x, tx = tid & 15, ty = tid >> 4;
  float at[2][2] = {{0,0},{0,0}}, a0[2][2] = {{0,0},{0,0}}, a1[2][2] = {{0,0},{0,0}}, a2[2][2] = {{0,0},{0,0}};
  const float* G = gamma + ((size_t)(cbi*NK))*NPIX;
  int r = tid >> 3, jj = (tid & 7)*4;
  const float* Zd = zrow(fgbg, cfcb, qf, br, b, d0 + r);
  const float* Ze = zrow(fgbg, cfcb, qf, br, b, e0 + r);
  for(int nc = 0; nc < 72; nc++){
    int n0 = seg*2304 + nc*32;
    __syncthreads();
    {
      float4 v = *(const float4*)(Zd + n0 + jj);
      SD[jj][r] = v.x; SD[jj+1][r] = v.y; SD[jj+2][r] = v.z; SD[jj+3][r] = v.w;
      v = *(const float4*)(Ze + n0 + jj);
      SE[jj][r] = v.x; SE[jj+1][r] = v.y; SE[jj+2][r] = v.z; SE[jj+3][r] = v.w;
      if(tid < 128) SG[tid & 31][tid >> 5] = G[(size_t)(tid >> 5)*NPIX + n0 + (tid & 31)];
    }
    __syncthreads();
    #pragma unroll 4
    for(int nn = 0; nn < 32; nn++){
      float4 g4 = *(const float4*)(&SG[nn][0]);
      float zd0 = SD[nn][2*ty], zd1 = SD[nn][2*ty + 1];
      float ze0 = SE[nn][2*tx], ze1 = SE[nn][2*tx + 1];
      #pragma unroll
      for(int i = 0; i < 2; i++){
        float zd = i ? zd1 : zd0;
        #pragma unroll
        for(int j = 0; j < 2; j++){
          float ze = j ? ze1 : ze0;
          float pr = zd*ze;
          at[i][j] += pr;
          a0[i][j] += g4.x*pr;
          a1[i][j] += g4.y*pr;
          a2[i][j] += g4.z*pr;
        }
      }
    }
  }
  size_t slot0 = (size_t)(seg*64 + cbi*4);
  size_t st = (size_t)ND*PITCH;
  #pragma unroll
  for(int i = 0; i < 2; i++){
    #pragma unroll
    for(int j = 0; j < 2; j++){
      int d = d0 + 2*ty + i, e = e0 + 2*tx + j;
      if(e >= d){
        size_t o = (slot0*ND + d)*PITCH + e;
        Mpart[o]        = a0[i][j];
        Mpart[o + st]   = a1[i][j];
        Mpart[o + 2*st] = a2[i][j];
        Mpart[o + 3*st] = at[i][j];
      }
    }
  }
}

// row/col d==128 strip of the second moment
__global__ __launch_bounds__(256) void k_covstrip(const float* fgbg, const float* cfcb, const float* qf,
                                                  const float* gamma, float* Mpart){
  __shared__ float rb[256];
  int e = blockIdx.x, cb = blockIdx.y, seg = blockIdx.z, tid = threadIdx.x;
  int br = cb >> 3, b = cb & 7;
  const float* Ze = zrow(fgbg, cfcb, qf, br, b, e);
  const float* CF = cfcb + (size_t)cb*NPIX;
  const float* G  = gamma + ((size_t)(cb*NK))*NPIX;
  float at = 0.f, a0 = 0.f, a1 = 0.f, a2 = 0.f;
  int n0 = seg*2304;
  for(int n = n0 + tid; n < n0 + 2304; n += 256){
    float pr = Ze[n]*CF[n];
    at += pr; a0 += G[n]*pr; a1 += G[NPIX + n]*pr; a2 += G[2*NPIX + n]*pr;
  }
  size_t base = ((size_t)(seg*64 + cb*4)*ND + e)*PITCH + 128;
  size_t st = (size_t)ND*PITCH;
  float t;
  t = blockSum256(a0, rb); if(tid == 0) Mpart[base]        = t;
  t = blockSum256(a1, rb); if(tid == 0) Mpart[base + st]   = t;
  t = blockSum256(a2, rb); if(tid == 0) Mpart[base + 2*st] = t;
  t = blockSum256(at, rb); if(tid == 0) Mpart[base + 3*st] = t;
}

__global__ __launch_bounds__(192) void k_covfin(const float* Mpart, const float* sumg, const float* mu,
                                                float* covb){
  int i = blockIdx.x, c = blockIdx.y, j = threadIdx.x;
  if(j > i) return;
  int k = c & 3, cb4 = c & ~3;
  size_t st = (size_t)ND*PITCH;
  float s = 0.f;
  if(k < 3){
    #pragma unroll
    for(int sg = 0; sg < 4; sg++) s += Mpart[((size_t)(sg*64 + c)*ND + j)*PITCH + i];
  } else {
    #pragma unroll
    for(int sg = 0; sg < 4; sg++){
      size_t base = ((size_t)(sg*64 + cb4)*ND + j)*PITCH + i;
      s += Mpart[base + 3*st] - Mpart[base] - Mpart[base + st] - Mpart[base + 2*st];
    }
  }
  float sgv = sumg[c];
  float v = s/sgv - mu[(size_t)c*ND + i]*mu[(size_t)c*ND + j];
  if(i == j) v += 1e-6f;
  covb[((size_t)c*ND + i)*PITCH + j] = v;
}

// ---------------- Cholesky + logdet + sample + L^-1 (per combo) ----------------

__global__ __launch_bounds__(256) void k_cholinv(const float* covb, const float* muv, const float* phiv,
                                                 const float* nzf, const float* nzb,
                                                 float* Wout, float* logdet, float* fs, float* dout){
  extern __shared__ float sh[];
  float* A   = sh;                 // ND x APITCH
  float* Wl  = sh + ND*APITCH;     // ND x ND
  float* col = Wl + ND*ND;         // 132
  __shared__ float rb[256];
  int c = blockIdx.x, tid = threadIdx.x;
  for(int idx = tid; idx < ND*ND; idx += 256){
    int i = idx / ND, j = idx - i*ND;
    if(j <= i) A[i*APITCH + j] = covb[((size_t)c*ND + i)*PITCH + j];
  }
  __syncthreads();
  // left-looking Cholesky, column parallel over rows
  for(int j = 0; j < ND; j++){
    float s = 0.f;
    bool act = (tid >= j && tid < ND);
    if(act){
      s = A[tid*APITCH + j];
      for(int k2 = 0; k2 < j; k2++) s -= A[tid*APITCH + k2]*A[j*APITCH + k2];
      if(tid == j) col[0] = s;
    }
    __syncthreads();
    if(act){
      float dj = sqrtf(col[0]);
      A[tid*APITCH + j] = (tid == j) ? dj : (s/dj);
    }
    __syncthreads();
  }
  // logdet
  float ld = (tid < ND) ? logf(A[tid*APITCH + tid]) : 0.f;
  float lsum = blockSum256(ld, rb);
  if(tid == 0) logdet[c] = 2.f*lsum;
  // sample: fs = (mu + L @ noise) * phi ; also write mu_stack output for fg branch
  int br = c >> 5, b = (c >> 2) & 7, kk = c & 3;
  const float* nz = (br ? nzb : nzf) + (size_t)(b*NK + kk)*ND;
  if(tid < ND) col[tid] = nz[tid];
  __syncthreads();
  if(tid < ND){
    float s = muv[(size_t)c*ND + tid];
    for(int e = 0; e <= tid; e++) s += A[tid*APITCH + e]*col[e];
    float v = s*phiv[c];
    fs[(size_t)c*ND + tid] = v;
    if(br == 0) dout[(size_t)kk*(NBATCH*ND) + (size_t)b*ND + tid] = v;
  }
  __syncthreads();
  // W = L^{-1}, column per thread, forward recurrence over rows
  for(int i = 0; i < ND; i++){
    if(tid <= i && tid < ND){
      float s = (i == tid) ? 1.f : 0.f;
      for(int k2 = 0; k2 < i; k2++){
        float w = Wl[k2*ND + tid];
        s -= (k2 >= tid) ? (A[i*APITCH + k2]*w) : 0.f;
      }
      Wl[i*ND + tid] = s / A[i*APITCH + i];
    }
    __syncthreads();
  }
  for(int idx = tid; idx < ND*ND; idx += 256){
    int i = idx / ND, j = idx - i*ND;
    if(j <= i) Wout[((size_t)c*ND + i)*PITCH + j] = Wl[i*ND + j];
  }
}

// ---------------- quad = || W (z - mu) ||^2 per pixel ----------------

__global__ __launch_bounds__(256) void k_quad(const float* fgbg, const float* cfcb, const float* qf,
                                              const float* Wg, const float* mu, float* quad){
  __shared__ float df[ND][66];
  __shared__ float qred[4][64];
  int c = blockIdx.y;
  int br = c >> 5, b = (c >> 2) & 7;
  int n0 = blockIdx.x*64;
  int tid = threadIdx.x;
  for(int idx = tid; idx < ND*16; idx += 256){
    int r = idx >> 4, sgi = idx & 15;
    const float* Zr = zrow(fgbg, cfcb, qf, br, b, r);
    float4 v = *(const float4*)(Zr + n0 + sgi*4);
    float m = mu[(size_t)c*ND + r];
    df[r][sgi*4 + 0] = v.x - m; df[r][sgi*4 + 1] = v.y - m;
    df[r][sgi*4 + 2] = v.z - m; df[r][sgi*4 + 3] = v.w - m;
  }
  __syncthreads();
  int lane = tid & 63, g = tid >> 6;
  const float* Wc = Wg + (size_t)c*ND*PITCH;
  float qp = 0.f;
  for(int ch = g; ch < 33; ch += 4){
    int d0 = ch*4;
    float y[4] = {0.f, 0.f, 0.f, 0.f};
    for(int e = 0; e < d0; e++){
      float x = df[e][lane];
      #pragma unroll
      for(int i = 0; i < 4; i++) y[i] += Wc[(size_t)(d0 + i)*PITCH + e]*x;
    }
    #pragma unroll
    for(int i = 0; i < 4; i++){
      int d = d0 + i;
      if(d < ND){
        float yy = y[i];
        for(int e = d0; e <= d; e++) yy += Wc[(size_t)d*PITCH + e]*df[e][lane];
        qp += yy*yy;
      }
    }
  }
  qred[g][lane] = qp;
  __syncthreads();
  if(tid < 64){
    float q = qred[0][tid] + qred[1][tid] + qred[2][tid] + qred[3][tid];
    quad[(size_t)c*NPIX + n0 + tid] = q;
  }
}

// ---------------- energy ----------------

__global__ __launch_bounds__(256) void k_energy(const float* quad, const float* logdet, const float* logphi,
                                                float* eacc){
  __shared__ float rb[256];
  int tid = threadIdx.x;
  int n = blockIdx.x*256 + tid, b = blockIdx.y, br = blockIdx.z;
  int c0 = (br*NBATCH + b)*NK;
  const float C0 = 118.54307078340277f;  // 0.5 * 129 * ln(2*pi)
  float l0 = -0.5f*quad[(size_t)(c0 + 0)*NPIX + n] - 0.5f*logdet[c0 + 0] - C0 + logphi[c0 + 0];
  float l1 = -0.5f*quad[(size_t)(c0 + 1)*NPIX + n] - 0.5f*logdet[c0 + 1] - C0 + logphi[c0 + 1];
  float l2 = -0.5f*quad[(size_t)(c0 + 2)*NPIX + n] - 0.5f*logdet[c0 + 2] - C0 + logphi[c0 + 2];
  float l3 = -0.5f*quad[(size_t)(c0 + 3)*NPIX + n] - 0.5f*logdet[c0 + 3] - C0 + logphi[c0 + 3];
  float mx = fmaxf(fmaxf(l0, l1), fmaxf(l2, l3));
  float lse = mx + logf(expf(l0 - mx) + expf(l1 - mx) + expf(l2 - mx) + expf(l3 - mx));
  float t = blockSum256(lse, rb);
  if(tid == 0) atomicAdd(&eacc[br], t);
}

__global__ void k_fin(const float* eacc, float* dout){
  int t = threadIdx.x;
  if(t < 2) dout[151584 + t] = -eacc[t] / (float)(NBATCH*NPIX);
}

// ---------------- discriminative prob map ----------------

__global__ __launch_bounds__(256) void k_prob(const float* fgbg, const float* cfcb, const float* qf,
                                              const float* fs, float* dout){
  __shared__ float MC[8][132];
  int b = blockIdx.y, tid = threadIdx.x;
  for(int idx = tid; idx < 8*ND; idx += 256){
    int m = idx / ND, d = idx - m*ND;
    int br = m >> 2, kk = m & 3;
    MC[m][d] = fs[(size_t)((br*NBATCH + b)*NK + kk)*ND + d];
  }
  __syncthreads();
  int n = blockIdx.x*256 + tid;
  float a[8] = {0,0,0,0,0,0,0,0};
  const float* Z0 = fgbg + ((size_t)(b*NC))*NPIX + n;  // br=0 (z_fg)
  for(int d = 0; d < NC; d++){
    float z = Z0[(size_t)d*NPIX];
    #pragma unroll
    for(int m = 0; m < 8; m++) a[m] += z*MC[m][d];
  }
  const float* Q = qf + ((size_t)(b*NC))*NPIX + n;
  for(int d = 0; d < NC; d++){
    float z = Q[(size_t)d*NPIX];
    #pragma unroll
    for(int m = 0; m < 8; m++) a[m] += z*MC[m][NC + d];
  }
  {
    float z = cfcb[(size_t)b*NPIX + n];
    #pragma unroll
    for(int m = 0; m < 8; m++) a[m] += z*MC[m][128];
  }
  float mx = a[0];
  #pragma unroll
  for(int m = 1; m < 8; m++) mx = fmaxf(mx, a[m]);
  float e[8]; float ssum = 0.f;
  #pragma unroll
  for(int m = 0; m < 8; m++){ e[m] = expf(a[m] - mx); ssum += e[m]; }
  float inv = 1.f/ssum;
  float Pf = (e[0] + e[1] + e[2] + e[3])*inv;
  float Pb = (e[4] + e[5] + e[6] + e[7])*inv;
  dout[4128 + ((size_t)(b*2))*NPIX + n]     = Pb;
  dout[4128 + ((size_t)(b*2 + 1))*NPIX + n] = Pf;
}

// ---------------- launcher ----------------

extern "C" void kernel_launch(void* const* d_in, const int* in_sizes, int n_in,
                              void* d_out, int out_size, void* d_ws, size_t ws_size,
                              hipStream_t stream){
  const float* sf  = (const float*)d_in[0];
  const float* smk = (const float*)d_in[1];
  const float* qfp = (const float*)d_in[2];
  const float* w1  = (const float*)d_in[3];
  const float* b1  = (const float*)d_in[4];
  const float* g1  = (const float*)d_in[5];
  const float* be1 = (const float*)d_in[6];
  const float* w2  = (const float*)d_in[7];
  const float* b2  = (const float*)d_in[8];
  const float* g2  = (const float*)d_in[9];
  const float* be2 = (const float*)d_in[10];
  const float* w3  = (const float*)d_in[11];
  const float* b3  = (const float*)d_in[12];
  const float* nzf = (const float*)d_in[13];
  const float* nzb = (const float*)d_in[14];
  float* out = (float*)d_out;
  float* W   = (float*)d_ws;

  constexpr size_t OFF_FGBG  = 0;
  constexpr size_t SZ_FGBG   = (size_t)2*NBATCH*NC*NPIX;      // 9,437,184
  constexpr size_t OFF_CFCB  = OFF_FGBG + SZ_FGBG;
  constexpr size_t SZ_CFCB   = (size_t)2*NBATCH*NPIX;         // 147,456
  constexpr size_t OFF_H1    = OFF_CFCB + SZ_CFCB;
  constexpr size_t SZ_H1     = (size_t)2*NBATCH*NC*NPIX;      // 9,437,184
  constexpr size_t OFF_MPART = OFF_H1;                        // reuse after gamma
  constexpr size_t SZ_MPART  = (size_t)4*NCOMBO*ND*PITCH;     // 4,359,168
  constexpr size_t OFF_COVB  = OFF_H1 + SZ_MPART;
  constexpr size_t OFF_H2    = OFF_H1 + SZ_H1;
  constexpr size_t SZ_H2     = (size_t)2*NBATCH*16*NPIX;      // 2,359,296
  constexpr size_t OFF_W     = OFF_H2;                        // reuse after gamma
  constexpr size_t OFF_GAMMA = OFF_H2 + SZ_H2;
  constexpr size_t SZ_GAMMA  = (size_t)2*NBATCH*NK*NPIX;      // 589,824
  constexpr size_t OFF_QUAD  = OFF_GAMMA + SZ_GAMMA;
  constexpr size_t SZ_QUAD   = SZ_GAMMA;
  constexpr size_t OFF_SC    = OFF_QUAD + SZ_QUAD;

  float* fgbg  = W + OFF_FGBG;
  float* cfcb  = W + OFF_CFCB;
  float* h1    = W + OFF_H1;
  float* h2    = W + OFF_H2;
  float* gamma = W + OFF_GAMMA;
  float* quad  = W + OFF_QUAD;
  float* Mpart = W + OFF_MPART;
  float* covb  = W + OFF_COVB;
  float* Winv  = W + OFF_W;
  float* sc    = W + OFF_SC;
  float* mean1 = sc;        float* rstd1 = sc + 128;
  float* mean2 = sc + 256;  float* rstd2 = sc + 288;
  float* sumg  = sc + 320;  float* eacc  = sc + 384;   // zeroed together (66 floats)
  float* phi   = sc + 388;  float* logphi = sc + 452;
  float* mu    = sc + 516;
  float* logdetv = sc + 8772;
  float* fsv   = sc + 8836;

  hipMemsetAsync(sumg, 0, 66*sizeof(float), stream);

  k_prep   <<<dim3(36, 8),      256, 0, stream>>>(sf, smk, qfp, fgbg, cfcb);
  k_conv1  <<<dim3(36, 8, 2),   256, 0, stream>>>(fgbg, cfcb, qfp, w1, b1, h1);
  k_bnstats<<<dim3(64, 2),      256, 0, stream>>>(h1, mean1, rstd1, 64);
  k_conv2  <<<dim3(36, 8, 2),   256, 0, stream>>>(h1, mean1, rstd1, g1, be1, w2, b2, h2);
  k_bnstats<<<dim3(16, 2),      256, 0, stream>>>(h2, mean2, rstd2, 16);
  k_gamma  <<<dim3(36, 8, 2),   256, 0, stream>>>(h2, mean2, rstd2, g2, be2, w3, b3, gamma, sumg);
  k_musum  <<<dim3(129, 8, 2),  256, 0, stream>>>(fgbg, cfcb, qfp, gamma, mu);
  k_phimufin<<<1,               256, 0, stream>>>(sumg, phi, logphi, mu);
  k_cov    <<<dim3(10, 16, 4),  256, 0, stream>>>(fgbg, cfcb, qfp, gamma, Mpart);
  k_covstrip<<<dim3(129, 16, 4),256, 0, stream>>>(fgbg, cfcb, qfp, gamma, Mpart);
  k_covfin <<<dim3(129, 64),    192, 0, stream>>>(Mpart, sumg, mu, covb);
  k_cholinv<<<64, 256, (ND*APITCH + ND*ND + 132)*sizeof(float), stream>>>(covb, mu, phi, nzf, nzb,
                                                                          Winv, logdetv, fsv, out);
  k_quad   <<<dim3(144, 64),    256, 0, stream>>>(fgbg, cfcb, qfp, Winv, mu, quad);
  k_energy <<<dim3(36, 8, 2),   256, 0, stream>>>(quad, logdetv, logphi, eacc);
  k_prob   <<<dim3(36, 8),      256, 0, stream>>>(fgbg, cfcb, qfp, fsv, out);
  k_fin    <<<1, 64, 0, stream>>>(eacc, out);
}

// Round 2
// 1644.377 us; speedup vs baseline: 1.2236x; 1.2236x over previous
//
#include <hip/hip_runtime.h>
#include <math.h>

#define NPIX 9216
#define NBATCH 8
#define NC 64
#define ND 129
#define NK 4
#define NCOMBO 64   // 2 branches * 8 batch * 4 k
#define PITCH 132   // row pitch for 129-wide matrices in global
#define APITCH 131  // LDS pitch for cholesky (131%32=3 -> bank-clean column access)

// ---------------- helpers ----------------

__device__ __forceinline__ const float* zrow(const float* fgbg, const float* cfcb, const float* qf,
                                             int br, int b, int d){
  if(d < NC)        return fgbg + ((size_t)((br*NBATCH + b)*NC + d))*NPIX;
  else if(d < 2*NC) return qf   + ((size_t)(b*NC + (d - NC)))*NPIX;
  else              return cfcb + (size_t)(br*NBATCH + b)*NPIX;
}

__device__ __forceinline__ float blockSum256(float v, float* rb){
  int tid = threadIdx.x;
  rb[tid] = v; __syncthreads();
  #pragma unroll
  for(int s = 128; s > 0; s >>= 1){
    if(tid < s) rb[tid] += rb[tid + s];
    __syncthreads();
  }
  float r = rb[0]; __syncthreads();
  return r;
}

// ---------------- stage 1: fg/bg/cosine ----------------

__global__ __launch_bounds__(256) void k_prep(const float* sf, const float* smk, const float* qf,
                                              float* fgbg, float* cfcb){
  int tid = threadIdx.x, b = blockIdx.y;
  int n = blockIdx.x*256 + tid;
  float m = smk[(size_t)b*NPIX + n];
  const float* S = sf + ((size_t)(b*NC))*NPIX + n;
  const float* Q = qf + ((size_t)(b*NC))*NPIX + n;
  float* FG = fgbg + ((size_t)(b*NC))*NPIX + n;
  float* BG = fgbg + ((size_t)((NBATCH + b)*NC))*NPIX + n;
  float df = 0.f, db = 0.f, nf = 0.f, nb_ = 0.f, nq = 0.f;
  #pragma unroll 4
  for(int c = 0; c < NC; c++){
    float s = S[(size_t)c*NPIX], q = Q[(size_t)c*NPIX];
    float f = s*m, g = s - f;
    FG[(size_t)c*NPIX] = f; BG[(size_t)c*NPIX] = g;
    df += f*q; db += g*q; nf += f*f; nb_ += g*g; nq += q*q;
  }
  float rq = fmaxf(sqrtf(nq), 1e-8f);
  cfcb[(size_t)b*NPIX + n]            = df / (fmaxf(sqrtf(nf),  1e-8f) * rq);
  cfcb[(size_t)(NBATCH + b)*NPIX + n] = db / (fmaxf(sqrtf(nb_), 1e-8f) * rq);
}

// ---------------- estimator ----------------

__global__ __launch_bounds__(256) void k_conv1(const float* fgbg, const float* cfcb, const float* qf,
                                               const float* w1, const float* b1, float* h1){
  __shared__ float Ws[ND*NC];
  __shared__ float B1[NC];
  int tid = threadIdx.x, b = blockIdx.y, br = blockIdx.z;
  for(int i = tid; i < ND*NC; i += 256) Ws[i] = w1[i];
  if(tid < NC) B1[tid] = b1[tid];
  __syncthreads();
  int n = blockIdx.x*256 + tid;
  float acc[NC];
  #pragma unroll
  for(int j = 0; j < NC; j++) acc[j] = B1[j];
  const float* Z0 = fgbg + ((size_t)((br*NBATCH + b)*NC))*NPIX + n;
  #pragma unroll 2
  for(int d = 0; d < NC; d++){
    float z = Z0[(size_t)d*NPIX];
    #pragma unroll
    for(int j = 0; j < NC; j++) acc[j] += z*Ws[d*NC + j];
  }
  const float* Q = qf + ((size_t)(b*NC))*NPIX + n;
  #pragma unroll 2
  for(int d = 0; d < NC; d++){
    float z = Q[(size_t)d*NPIX];
    #pragma unroll
    for(int j = 0; j < NC; j++) acc[j] += z*Ws[(NC + d)*NC + j];
  }
  {
    float z = cfcb[(size_t)(br*NBATCH + b)*NPIX + n];
    #pragma unroll
    for(int j = 0; j < NC; j++) acc[j] += z*Ws[128*NC + j];
  }
  float* O = h1 + ((size_t)((br*NBATCH + b)*NC))*NPIX + n;
  #pragma unroll
  for(int j = 0; j < NC; j++) O[(size_t)j*NPIX] = acc[j];
}

// BN batch-stats: parallel partial sums + atomics, then tiny finalize
__global__ __launch_bounds__(256) void k_bnpart(const float* x, float* part, int C){
  __shared__ float rb[256];
  int c = blockIdx.x, br = blockIdx.y, b = blockIdx.z, tid = threadIdx.x;
  const float4* X = (const float4*)(x + ((size_t)((br*NBATCH + b)*C + c))*NPIX);
  float s = 0.f, ss = 0.f;
  for(int n = tid; n < NPIX/4; n += 256){
    float4 v = X[n];
    s  += v.x + v.y + v.z + v.w;
    ss += v.x*v.x + v.y*v.y + v.z*v.z + v.w*v.w;
  }
  float S  = blockSum256(s,  rb);
  float SS = blockSum256(ss, rb);
  if(tid == 0){
    atomicAdd(&part[(size_t)(br*C + c)*2],     S);
    atomicAdd(&part[(size_t)(br*C + c)*2 + 1], SS);
  }
}

__global__ void k_bnfin(const float* part, float* meanv, float* rstdv, int C){
  int i = blockIdx.x*64 + threadIdx.x;
  if(i < 2*C){
    float m = part[(size_t)i*2]     / (float)(NBATCH*NPIX);
    float v = part[(size_t)i*2 + 1] / (float)(NBATCH*NPIX) - m*m;
    meanv[i] = m;
    rstdv[i] = 1.0f / sqrtf(v + 1e-5f);
  }
}

__global__ __launch_bounds__(256) void k_conv2(const float* h1, const float* mean1, const float* rstd1,
                                               const float* g1, const float* be1,
                                               const float* w2, const float* b2, float* h2){
  __shared__ float Ws[NC*16];
  __shared__ float Pm[NC], Pr[NC], Pg[NC], Pb[NC];
  __shared__ float B2[16];
  int tid = threadIdx.x, b = blockIdx.y, br = blockIdx.z;
  for(int i = tid; i < NC*16; i += 256) Ws[i] = w2[i];
  if(tid < NC){ Pm[tid] = mean1[br*NC + tid]; Pr[tid] = rstd1[br*NC + tid]; Pg[tid] = g1[tid]; Pb[tid] = be1[tid]; }
  if(tid < 16) B2[tid] = b2[tid];
  __syncthreads();
  int n = blockIdx.x*256 + tid;
  const float* X = h1 + ((size_t)((br*NBATCH + b)*NC))*NPIX + n;
  float acc[16];
  #pragma unroll
  for(int j = 0; j < 16; j++) acc[j] = B2[j];
  for(int c = 0; c < NC; c++){
    float v = (X[(size_t)c*NPIX] - Pm[c])*Pr[c]*Pg[c] + Pb[c];
    v = fmaxf(v, 0.f);
    #pragma unroll
    for(int j = 0; j < 16; j++) acc[j] += v*Ws[c*16 + j];
  }
  float* O = h2 + ((size_t)((br*NBATCH + b)*16))*NPIX + n;
  #pragma unroll
  for(int j = 0; j < 16; j++) O[(size_t)j*NPIX] = acc[j];
}

__global__ __launch_bounds__(256) void k_gamma(const float* h2, const float* mean2, const float* rstd2,
                                               const float* g2, const float* be2,
                                               const float* w3, const float* b3,
                                               float* gamma, float* sumg){
  __shared__ float W3[16*4];
  __shared__ float Pm[16], Pr[16], Pg[16], Pb[16];
  __shared__ float B3[4];
  __shared__ float rb[256];
  int tid = threadIdx.x, b = blockIdx.y, br = blockIdx.z;
  if(tid < 64) W3[tid] = w3[tid];
  if(tid < 4)  B3[tid] = b3[tid];
  if(tid < 16){ Pm[tid] = mean2[br*16 + tid]; Pr[tid] = rstd2[br*16 + tid]; Pg[tid] = g2[tid]; Pb[tid] = be2[tid]; }
  __syncthreads();
  int n = blockIdx.x*256 + tid;
  const float* X = h2 + ((size_t)((br*NBATCH + b)*16))*NPIX + n;
  float l0 = B3[0], l1 = B3[1], l2 = B3[2], l3 = B3[3];
  #pragma unroll
  for(int c = 0; c < 16; c++){
    float v = (X[(size_t)c*NPIX] - Pm[c])*Pr[c]*Pg[c] + Pb[c];
    v = fmaxf(v, 0.f);
    l0 += v*W3[c*4 + 0]; l1 += v*W3[c*4 + 1]; l2 += v*W3[c*4 + 2]; l3 += v*W3[c*4 + 3];
  }
  float mx = fmaxf(fmaxf(l0, l1), fmaxf(l2, l3));
  float e0 = expf(l0 - mx), e1 = expf(l1 - mx), e2 = expf(l2 - mx), e3 = expf(l3 - mx);
  float inv = 1.0f / (e0 + e1 + e2 + e3);
  float q0 = e0*inv, q1 = e1*inv, q2 = e2*inv, q3 = e3*inv;
  float* G = gamma + ((size_t)((br*NBATCH + b)*NK))*NPIX + n;
  G[0] = q0; G[NPIX] = q1; G[2*NPIX] = q2; G[3*NPIX] = q3;
  int cb = br*NBATCH + b;
  float t;
  t = blockSum256(q0, rb); if(tid == 0) atomicAdd(&sumg[cb*4 + 0], t);
  t = blockSum256(q1, rb); if(tid == 0) atomicAdd(&sumg[cb*4 + 1], t);
  t = blockSum256(q2, rb); if(tid == 0) atomicAdd(&sumg[cb*4 + 2], t);
  t = blockSum256(q3, rb); if(tid == 0) atomicAdd(&sumg[cb*4 + 3], t);
}

// ---------------- GMM: mu ----------------

__global__ __launch_bounds__(256) void k_musum(const float* fgbg, const float* cfcb, const float* qf,
                                               const float* gamma, float* musum){
  __shared__ float rb[256];
  int d = blockIdx.x, b = blockIdx.y, br = blockIdx.z, tid = threadIdx.x;
  const float* Z = zrow(fgbg, cfcb, qf, br, b, d);
  const float* G = gamma + ((size_t)((br*NBATCH + b)*NK))*NPIX;
  float a0 = 0.f, a1 = 0.f, a2 = 0.f, a3 = 0.f;
  for(int n = tid; n < NPIX; n += 256){
    float z = Z[n];
    a0 += G[n]*z; a1 += G[NPIX + n]*z; a2 += G[2*NPIX + n]*z; a3 += G[3*NPIX + n]*z;
  }
  int cb = br*NBATCH + b;
  float t;
  t = blockSum256(a0, rb); if(tid == 0) musum[((size_t)(cb*4 + 0))*ND + d] = t;
  t = blockSum256(a1, rb); if(tid == 0) musum[((size_t)(cb*4 + 1))*ND + d] = t;
  t = blockSum256(a2, rb); if(tid == 0) musum[((size_t)(cb*4 + 2))*ND + d] = t;
  t = blockSum256(a3, rb); if(tid == 0) musum[((size_t)(cb*4 + 3))*ND + d] = t;
}

__global__ __launch_bounds__(256) void k_phimufin(const float* sumg, float* phi, float* logphi, float* mu){
  int tid = threadIdx.x;
  if(tid < NCOMBO){
    float sg = sumg[tid];
    float p = sg / (float)NPIX;
    phi[tid] = p;
    logphi[tid] = logf(p + 1e-12f);
  }
  for(int i = tid; i < NCOMBO*ND; i += 256){
    int c = i / ND;
    mu[i] = mu[i] / sumg[c];
  }
}

// ---------------- GMM: weighted second moment (upper triangle, tiles of 32) ----------------

__global__ __launch_bounds__(256) void k_cov(const float* fgbg, const float* cfcb, const float* qf,
                                             const float* gamma, float* Mpart){
  __shared__ float SD[32][34];
  __shared__ float SE[32][34];
  __shared__ __align__(16) float SG[32][4];
  int p = blockIdx.x, cbi = blockIdx.y, seg = blockIdx.z;
  int ti, tj;
  if(p < 4){ ti = 0; tj = p; } else if(p < 7){ ti = 1; tj = p - 3; }
  else if(p < 9){ ti = 2; tj = p - 5; } else { ti = 3; tj = 3; }
  int br = cbi >> 3, b = cbi & 7;
  int d0 = ti*32, e0 = tj*32;
  int tid = threadIdx.x, tx = tid & 15, ty = tid >> 4;
  float at[2][2] = {{0,0},{0,0}}, a0[2][2] = {{0,0},{0,0}}, a1[2][2] = {{0,0},{0,0}}, a2[2][2] = {{0,0},{0,0}};
  const float* G = gamma + ((size_t)(cbi*NK))*NPIX;
  int r = tid >> 3, jj = (tid & 7)*4;
  const float* Zd = zrow(fgbg, cfcb, qf, br, b, d0 + r);
  const float* Ze = zrow(fgbg, cfcb, qf, br, b, e0 + r);
  for(int nc = 0; nc < 72; nc++){
    int n0 = seg*2304 + nc*32;
    __syncthreads();
    {
      float4 v = *(const float4*)(Zd + n0 + jj);
      SD[jj][r] = v.x; SD[jj+1][r] = v.y; SD[jj+2][r] = v.z; SD[jj+3][r] = v.w;
      v = *(const float4*)(Ze + n0 + jj);
      SE[jj][r] = v.x; SE[jj+1][r] = v.y; SE[jj+2][r] = v.z; SE[jj+3][r] = v.w;
      if(tid < 128) SG[tid & 31][tid >> 5] = G[(size_t)(tid >> 5)*NPIX + n0 + (tid & 31)];
    }
    __syncthreads();
    #pragma unroll 4
    for(int nn = 0; nn < 32; nn++){
      float4 g4 = *(const float4*)(&SG[nn][0]);
      float zd0 = SD[nn][2*ty], zd1 = SD[nn][2*ty + 1];
      float ze0 = SE[nn][2*tx], ze1 = SE[nn][2*tx + 1];
      #pragma unroll
      for(int i = 0; i < 2; i++){
        float zd = i ? zd1 : zd0;
        #pragma unroll
        for(int j = 0; j < 2; j++){
          float ze = j ? ze1 : ze0;
          float pr = zd*ze;
          at[i][j] += pr;
          a0[i][j] += g4.x*pr;
          a1[i][j] += g4.y*pr;
          a2[i][j] += g4.z*pr;
        }
      }
    }
  }
  size_t slot0 = (size_t)(seg*64 + cbi*4);
  size_t st = (size_t)ND*PITCH;
  #pragma unroll
  for(int i = 0; i < 2; i++){
    #pragma unroll
    for(int j = 0; j < 2; j++){
      int d = d0 + 2*ty + i, e = e0 + 2*tx + j;
      if(e >= d){
        size_t o = (slot0*ND + d)*PITCH + e;
        Mpart[o]        = a0[i][j];
        Mpart[o + st]   = a1[i][j];
        Mpart[o + 2*st] = a2[i][j];
        Mpart[o + 3*st] = at[i][j];
      }
    }
  }
}

__global__ __launch_bounds__(256) void k_covstrip(const float* fgbg, const float* cfcb, const float* qf,
                                                  const float* gamma, float* Mpart){
  __shared__ float rb[256];
  int e = blockIdx.x, cb = blockIdx.y, seg = blockIdx.z, tid = threadIdx.x;
  int br = cb >> 3, b = cb & 7;
  const float* Ze = zrow(fgbg, cfcb, qf, br, b, e);
  const float* CF = cfcb + (size_t)cb*NPIX;
  const float* G  = gamma + ((size_t)(cb*NK))*NPIX;
  float at = 0.f, a0 = 0.f, a1 = 0.f, a2 = 0.f;
  int n0 = seg*2304;
  for(int n = n0 + tid; n < n0 + 2304; n += 256){
    float pr = Ze[n]*CF[n];
    at += pr; a0 += G[n]*pr; a1 += G[NPIX + n]*pr; a2 += G[2*NPIX + n]*pr;
  }
  size_t base = ((size_t)(seg*64 + cb*4)*ND + e)*PITCH + 128;
  size_t st = (size_t)ND*PITCH;
  float t;
  t = blockSum256(a0, rb); if(tid == 0) Mpart[base]        = t;
  t = blockSum256(a1, rb); if(tid == 0) Mpart[base + st]   = t;
  t = blockSum256(a2, rb); if(tid == 0) Mpart[base + 2*st] = t;
  t = blockSum256(at, rb); if(tid == 0) Mpart[base + 3*st] = t;
}

__global__ __launch_bounds__(192) void k_covfin(const float* Mpart, const float* sumg, const float* mu,
                                                float* covb){
  int i = blockIdx.x, c = blockIdx.y, j = threadIdx.x;
  if(j > i) return;
  int k = c & 3, cb4 = c & ~3;
  size_t st = (size_t)ND*PITCH;
  float s = 0.f;
  if(k < 3){
    #pragma unroll
    for(int sg = 0; sg < 4; sg++) s += Mpart[((size_t)(sg*64 + c)*ND + j)*PITCH + i];
  } else {
    #pragma unroll
    for(int sg = 0; sg < 4; sg++){
      size_t base = ((size_t)(sg*64 + cb4)*ND + j)*PITCH + i;
      s += Mpart[base + 3*st] - Mpart[base] - Mpart[base + st] - Mpart[base + 2*st];
    }
  }
  float sgv = sumg[c];
  float v = s/sgv - mu[(size_t)c*ND + i]*mu[(size_t)c*ND + j];
  if(i == j) v += 1e-6f;
  covb[((size_t)c*ND + i)*PITCH + j] = v;
}

// ---------------- Cholesky + logdet + sample + L^-1 (per combo) ----------------
// Right-looking rank-1-update Cholesky (LDL-ish raw columns, deferred scaling),
// one barrier per column; inverse = barrier-free column-per-thread forward subst.

__global__ __launch_bounds__(256) void k_cholinv(const float* covb, const float* muv, const float* phiv,
                                                 const float* nzf, const float* nzb,
                                                 float* Wout, float* logdet, float* fs, float* dout){
  extern __shared__ float sh[];
  float* A    = sh;                    // ND x APITCH, lower triangle (raw V, then L)
  float* Wl   = sh + ND*APITCH;        // column-major: Wl[c*ND + i]
  float* rs   = Wl + ND*ND;            // 132: 1/sqrt(d_j) == 1/L[j][j]
  float* cbuf = rs + 132;              // 2: double-buffered 1/diag
  __shared__ float rb[256];
  int c = blockIdx.x, tid = threadIdx.x;
  for(int idx = tid; idx < ND*ND; idx += 256){
    int i = idx / ND, j = idx - i*ND;
    if(j <= i) A[i*APITCH + j] = covb[((size_t)c*ND + i)*PITCH + j];
  }
  if(tid == 0) cbuf[0] = 1.0f / A[0];   // tid 0 loaded A[0][0] at idx 0
  __syncthreads();
  // factorization: for col j, row i updates A[i][j+1..i] -= (A[i][j]/d_j) * A[k][j]
  for(int j = 0; j < ND-1; j++){
    float invd = cbuf[j & 1];
    int i = j + 1 + tid;
    if(i < ND){
      float* Ai = A + (size_t)i*APITCH;
      float f = Ai[j] * invd;
      const float* Cj = A + j;
      #pragma unroll 4
      for(int k = j + 1; k <= i; k++) Ai[k] -= f * Cj[(size_t)k*APITCH];
      if(tid == 0) cbuf[(j + 1) & 1] = 1.0f / Ai[j + 1];   // next diag is final
    }
    __syncthreads();
  }
  // column scaling: L[i][j] = V[i][j] * rsqrt(d_j)  (diag: d_j*rsqrt(d_j)=sqrt(d_j))
  if(tid < ND) rs[tid] = 1.0f / sqrtf(A[(size_t)tid*APITCH + tid]);
  __syncthreads();
  for(int idx = tid; idx < ND*ND; idx += 256){
    int i = idx / ND, j = idx - i*ND;
    if(j <= i) A[(size_t)i*APITCH + j] *= rs[j];
  }
  __syncthreads();
  // logdet = 2 * sum log L_jj
  float ld = (tid < ND) ? logf(A[(size_t)tid*APITCH + tid]) : 0.f;
  float lsum = blockSum256(ld, rb);
  if(tid == 0) logdet[c] = 2.f*lsum;
  // sample: fs = (mu + L @ noise) * phi
  int br = c >> 5, b = (c >> 2) & 7, kk = c & 3;
  const float* nz = (br ? nzb : nzf) + (size_t)(b*NK + kk)*ND;
  if(tid < ND){
    const float* Ar = A + (size_t)tid*APITCH;
    float s = muv[(size_t)c*ND + tid];
    #pragma unroll 4
    for(int e = 0; e <= tid; e++) s += Ar[e]*nz[e];
    float v = s*phiv[c];
    fs[(size_t)c*ND + tid] = v;
    if(br == 0) dout[(size_t)kk*(NBATCH*ND) + (size_t)b*ND + tid] = v;
  }
  // W = L^{-1}: thread cc owns column cc, barrier-free forward substitution
  {
    int cc = tid;
    float* Wc = Wl + (size_t)cc*ND;
    for(int i = 0; i < ND; i++){
      if(cc <= i && cc < ND){
        float s = (i == cc) ? 1.f : 0.f;
        const float* Ar = A + (size_t)i*APITCH;
        #pragma unroll 4
        for(int k = cc; k < i; k++) s -= Ar[k]*Wc[k];
        Wc[i] = s * rs[i];
      }
    }
  }
  __syncthreads();
  for(int idx = tid; idx < ND*ND; idx += 256){
    int i = idx / ND, j = idx - i*ND;
    if(j <= i) Wout[((size_t)c*ND + i)*PITCH + j] = Wl[(size_t)j*ND + i];
  }
}

// ---------------- quad = || W (z - mu) ||^2 per pixel ----------------

__global__ __launch_bounds__(256) void k_quad(const float* fgbg, const float* cfcb, const float* qf,
                                              const float* Wg, const float* mu, float* quad){
  __shared__ float df[ND][66];
  __shared__ float qred[4][64];
  int c = blockIdx.y;
  int br = c >> 5, b = (c >> 2) & 7;
  int n0 = blockIdx.x*64;
  int tid = threadIdx.x;
  for(int idx = tid; idx < ND*16; idx += 256){
    int r = idx >> 4, sgi = idx & 15;
    const float* Zr = zrow(fgbg, cfcb, qf, br, b, r);
    float4 v = *(const float4*)(Zr + n0 + sgi*4);
    float m = mu[(size_t)c*ND + r];
    df[r][sgi*4 + 0] = v.x - m; df[r][sgi*4 + 1] = v.y - m;
    df[r][sgi*4 + 2] = v.z - m; df[r][sgi*4 + 3] = v.w - m;
  }
  __syncthreads();
  int lane = tid & 63, g = tid >> 6;
  const float* Wc = Wg + (size_t)c*ND*PITCH;
  float qp = 0.f;
  for(int ch = g; ch < 33; ch += 4){
    int d0 = ch*4;
    float y[4] = {0.f, 0.f, 0.f, 0.f};
    for(int e = 0; e < d0; e++){
      float x = df[e][lane];
      #pragma unroll
      for(int i = 0; i < 4; i++) y[i] += Wc[(size_t)(d0 + i)*PITCH + e]*x;
    }
    #pragma unroll
    for(int i = 0; i < 4; i++){
      int d = d0 + i;
      if(d < ND){
        float yy = y[i];
        for(int e = d0; e <= d; e++) yy += Wc[(size_t)d*PITCH + e]*df[e][lane];
        qp += yy*yy;
      }
    }
  }
  qred[g][lane] = qp;
  __syncthreads();
  if(tid < 64){
    float q = qred[0][tid] + qred[1][tid] + qred[2][tid] + qred[3][tid];
    quad[(size_t)c*NPIX + n0 + tid] = q;
  }
}

// ---------------- energy ----------------

__global__ __launch_bounds__(256) void k_energy(const float* quad, const float* logdet, const float* logphi,
                                                float* eacc){
  __shared__ float rb[256];
  int tid = threadIdx.x;
  int n = blockIdx.x*256 + tid, b = blockIdx.y, br = blockIdx.z;
  int c0 = (br*NBATCH + b)*NK;
  const float C0 = 118.54307078340277f;  // 0.5 * 129 * ln(2*pi)
  float l0 = -0.5f*quad[(size_t)(c0 + 0)*NPIX + n] - 0.5f*logdet[c0 + 0] - C0 + logphi[c0 + 0];
  float l1 = -0.5f*quad[(size_t)(c0 + 1)*NPIX + n] - 0.5f*logdet[c0 + 1] - C0 + logphi[c0 + 1];
  float l2 = -0.5f*quad[(size_t)(c0 + 2)*NPIX + n] - 0.5f*logdet[c0 + 2] - C0 + logphi[c0 + 2];
  float l3 = -0.5f*quad[(size_t)(c0 + 3)*NPIX + n] - 0.5f*logdet[c0 + 3] - C0 + logphi[c0 + 3];
  float mx = fmaxf(fmaxf(l0, l1), fmaxf(l2, l3));
  float lse = mx + logf(expf(l0 - mx) + expf(l1 - mx) + expf(l2 - mx) + expf(l3 - mx));
  float t = blockSum256(lse, rb);
  if(tid == 0) atomicAdd(&eacc[br], t);
}

__global__ void k_fin(const float* eacc, float* dout){
  int t = threadIdx.x;
  if(t < 2) dout[151584 + t] = -eacc[t] / (float)(NBATCH*NPIX);
}

// ---------------- discriminative prob map ----------------

__global__ __launch_bounds__(256) void k_prob(const float* fgbg, const float* cfcb, const float* qf,
                                              const float* fs, float* dout){
  __shared__ float MC[8][132];
  int b = blockIdx.y, tid = threadIdx.x;
  for(int idx = tid; idx < 8*ND; idx += 256){
    int m = idx / ND, d = idx - m*ND;
    int br = m >> 2, kk = m & 3;
    MC[m][d] = fs[(size_t)((br*NBATCH + b)*NK + kk)*ND + d];
  }
  __syncthreads();
  int n = blockIdx.x*256 + tid;
  float a[8] = {0,0,0,0,0,0,0,0};
  const float* Z0 = fgbg + ((size_t)(b*NC))*NPIX + n;
  for(int d = 0; d < NC; d++){
    float z = Z0[(size_t)d*NPIX];
    #pragma unroll
    for(int m = 0; m < 8; m++) a[m] += z*MC[m][d];
  }
  const float* Q = qf + ((size_t)(b*NC))*NPIX + n;
  for(int d = 0; d < NC; d++){
    float z = Q[(size_t)d*NPIX];
    #pragma unroll
    for(int m = 0; m < 8; m++) a[m] += z*MC[m][NC + d];
  }
  {
    float z = cfcb[(size_t)b*NPIX + n];
    #pragma unroll
    for(int m = 0; m < 8; m++) a[m] += z*MC[m][128];
  }
  float mx = a[0];
  #pragma unroll
  for(int m = 1; m < 8; m++) mx = fmaxf(mx, a[m]);
  float e[8]; float ssum = 0.f;
  #pragma unroll
  for(int m = 0; m < 8; m++){ e[m] = expf(a[m] - mx); ssum += e[m]; }
  float inv = 1.f/ssum;
  float Pf = (e[0] + e[1] + e[2] + e[3])*inv;
  float Pb = (e[4] + e[5] + e[6] + e[7])*inv;
  dout[4128 + ((size_t)(b*2))*NPIX + n]     = Pb;
  dout[4128 + ((size_t)(b*2 + 1))*NPIX + n] = Pf;
}

// ---------------- launcher ----------------

extern "C" void kernel_launch(void* const* d_in, const int* in_sizes, int n_in,
                              void* d_out, int out_size, void* d_ws, size_t ws_size,
                              hipStream_t stream){
  const float* sf  = (const float*)d_in[0];
  const float* smk = (const float*)d_in[1];
  const float* qfp = (const float*)d_in[2];
  const float* w1  = (const float*)d_in[3];
  const float* b1  = (const float*)d_in[4];
  const float* g1  = (const float*)d_in[5];
  const float* be1 = (const float*)d_in[6];
  const float* w2  = (const float*)d_in[7];
  const float* b2  = (const float*)d_in[8];
  const float* g2  = (const float*)d_in[9];
  const float* be2 = (const float*)d_in[10];
  const float* w3  = (const float*)d_in[11];
  const float* b3  = (const float*)d_in[12];
  const float* nzf = (const float*)d_in[13];
  const float* nzb = (const float*)d_in[14];
  float* out = (float*)d_out;
  float* W   = (float*)d_ws;

  constexpr size_t OFF_FGBG  = 0;
  constexpr size_t SZ_FGBG   = (size_t)2*NBATCH*NC*NPIX;
  constexpr size_t OFF_CFCB  = OFF_FGBG + SZ_FGBG;
  constexpr size_t SZ_CFCB   = (size_t)2*NBATCH*NPIX;
  constexpr size_t OFF_H1    = OFF_CFCB + SZ_CFCB;
  constexpr size_t SZ_H1     = (size_t)2*NBATCH*NC*NPIX;
  constexpr size_t OFF_MPART = OFF_H1;
  constexpr size_t SZ_MPART  = (size_t)4*NCOMBO*ND*PITCH;
  constexpr size_t OFF_COVB  = OFF_H1 + SZ_MPART;
  constexpr size_t OFF_H2    = OFF_H1 + SZ_H1;
  constexpr size_t SZ_H2     = (size_t)2*NBATCH*16*NPIX;
  constexpr size_t OFF_W     = OFF_H2;
  constexpr size_t OFF_GAMMA = OFF_H2 + SZ_H2;
  constexpr size_t SZ_GAMMA  = (size_t)2*NBATCH*NK*NPIX;
  constexpr size_t OFF_QUAD  = OFF_GAMMA + SZ_GAMMA;
  constexpr size_t SZ_QUAD   = SZ_GAMMA;
  constexpr size_t OFF_SC    = OFF_QUAD + SZ_QUAD;

  float* fgbg  = W + OFF_FGBG;
  float* cfcb  = W + OFF_CFCB;
  float* h1    = W + OFF_H1;
  float* h2    = W + OFF_H2;
  float* gamma = W + OFF_GAMMA;
  float* quad  = W + OFF_QUAD;
  float* Mpart = W + OFF_MPART;
  float* covb  = W + OFF_COVB;
  float* Winv  = W + OFF_W;
  float* sc    = W + OFF_SC;
  float* mean1 = sc;          float* rstd1  = sc + 128;
  float* mean2 = sc + 256;    float* rstd2  = sc + 288;
  float* sumg  = sc + 320;    float* eacc   = sc + 384;   // zero region: sumg..bnp2 (386 floats)
  float* bnp1  = sc + 386;    float* bnp2   = sc + 642;
  float* phi   = sc + 706;    float* logphi = sc + 770;
  float* mu    = sc + 834;
  float* logdetv = sc + 9090;
  float* fsv   = sc + 9154;

  hipMemsetAsync(sumg, 0, 386*sizeof(float), stream);

  k_prep   <<<dim3(36, 8),      256, 0, stream>>>(sf, smk, qfp, fgbg, cfcb);
  k_conv1  <<<dim3(36, 8, 2),   256, 0, stream>>>(fgbg, cfcb, qfp, w1, b1, h1);
  k_bnpart <<<dim3(64, 2, 8),   256, 0, stream>>>(h1, bnp1, 64);
  k_bnfin  <<<2, 64,                0, stream>>>(bnp1, mean1, rstd1, 64);
  k_conv2  <<<dim3(36, 8, 2),   256, 0, stream>>>(h1, mean1, rstd1, g1, be1, w2, b2, h2);
  k_bnpart <<<dim3(16, 2, 8),   256, 0, stream>>>(h2, bnp2, 16);
  k_bnfin  <<<1, 64,                0, stream>>>(bnp2, mean2, rstd2, 16);
  k_gamma  <<<dim3(36, 8, 2),   256, 0, stream>>>(h2, mean2, rstd2, g2, be2, w3, b3, gamma, sumg);
  k_musum  <<<dim3(129, 8, 2),  256, 0, stream>>>(fgbg, cfcb, qfp, gamma, mu);
  k_phimufin<<<1,               256, 0, stream>>>(sumg, phi, logphi, mu);
  k_cov    <<<dim3(10, 16, 4),  256, 0, stream>>>(fgbg, cfcb, qfp, gamma, Mpart);
  k_covstrip<<<dim3(129, 16, 4),256, 0, stream>>>(fgbg, cfcb, qfp, gamma, Mpart);
  k_covfin <<<dim3(129, 64),    192, 0, stream>>>(Mpart, sumg, mu, covb);
  k_cholinv<<<64, 256, (ND*APITCH + ND*ND + 132 + 4)*sizeof(float), stream>>>(covb, mu, phi, nzf, nzb,
                                                                              Winv, logdetv, fsv, out);
  k_quad   <<<dim3(144, 64),    256, 0, stream>>>(fgbg, cfcb, qfp, Winv, mu, quad);
  k_energy <<<dim3(36, 8, 2),   256, 0, stream>>>(quad, logdetv, logphi, eacc);
  k_prob   <<<dim3(36, 8),      256, 0, stream>>>(fgbg, cfcb, qfp, fsv, out);
  k_fin    <<<1, 64, 0, stream>>>(eacc, out);
}

// Round 7
// 1476.949 us; speedup vs baseline: 1.3623x; 1.1134x over previous
//
#include <hip/hip_runtime.h>
#include <math.h>

#define NPIX 9216
#define NBATCH 8
#define NC 64
#define ND 129
#define NK 4
#define NCOMBO 64   // 2 branches * 8 batch * 4 k
#define PITCH 132   // row pitch for 129-wide matrices in global
#define APITCH 131  // LDS pitch for cholesky (131%32=3 -> bank-clean column access)
#define WPACK 8976  // packed triangular W floats per combo (4-aligned columns)

// ---------------- helpers ----------------

__device__ __forceinline__ const float* zrow(const float* fgbg, const float* cfcb, const float* qf,
                                             int br, int b, int d){
  if(d < NC)        return fgbg + ((size_t)((br*NBATCH + b)*NC + d))*NPIX;
  else if(d < 2*NC) return qf   + ((size_t)(b*NC + (d - NC)))*NPIX;
  else              return cfcb + (size_t)(br*NBATCH + b)*NPIX;
}

__device__ __forceinline__ float blockSum256(float v, float* rb){
  int tid = threadIdx.x;
  rb[tid] = v; __syncthreads();
  #pragma unroll
  for(int s = 128; s > 0; s >>= 1){
    if(tid < s) rb[tid] += rb[tid + s];
    __syncthreads();
  }
  float r = rb[0]; __syncthreads();
  return r;
}

// ---------------- stage 1: fg/bg/cosine ----------------

__global__ __launch_bounds__(256) void k_prep(const float* sf, const float* smk, const float* qf,
                                              float* fgbg, float* cfcb){
  int tid = threadIdx.x, b = blockIdx.y;
  int n = blockIdx.x*256 + tid;
  float m = smk[(size_t)b*NPIX + n];
  const float* S = sf + ((size_t)(b*NC))*NPIX + n;
  const float* Q = qf + ((size_t)(b*NC))*NPIX + n;
  float* FG = fgbg + ((size_t)(b*NC))*NPIX + n;
  float* BG = fgbg + ((size_t)((NBATCH + b)*NC))*NPIX + n;
  float df = 0.f, db = 0.f, nf = 0.f, nb_ = 0.f, nq = 0.f;
  #pragma unroll 4
  for(int c = 0; c < NC; c++){
    float s = S[(size_t)c*NPIX], q = Q[(size_t)c*NPIX];
    float f = s*m, g = s - f;
    FG[(size_t)c*NPIX] = f; BG[(size_t)c*NPIX] = g;
    df += f*q; db += g*q; nf += f*f; nb_ += g*g; nq += q*q;
  }
  float rq = fmaxf(sqrtf(nq), 1e-8f);
  cfcb[(size_t)b*NPIX + n]            = df / (fmaxf(sqrtf(nf),  1e-8f) * rq);
  cfcb[(size_t)(NBATCH + b)*NPIX + n] = db / (fmaxf(sqrtf(nb_), 1e-8f) * rq);
}

// ---------------- estimator ----------------

__global__ __launch_bounds__(256) void k_conv1(const float* fgbg, const float* cfcb, const float* qf,
                                               const float* w1, const float* b1, float* h1){
  __shared__ float Ws[ND*NC];
  __shared__ float B1[NC];
  int tid = threadIdx.x, b = blockIdx.y, br = blockIdx.z;
  for(int i = tid; i < ND*NC; i += 256) Ws[i] = w1[i];
  if(tid < NC) B1[tid] = b1[tid];
  __syncthreads();
  int n = blockIdx.x*256 + tid;
  float acc[NC];
  #pragma unroll
  for(int j = 0; j < NC; j++) acc[j] = B1[j];
  const float* Z0 = fgbg + ((size_t)((br*NBATCH + b)*NC))*NPIX + n;
  #pragma unroll 2
  for(int d = 0; d < NC; d++){
    float z = Z0[(size_t)d*NPIX];
    #pragma unroll
    for(int j = 0; j < NC; j++) acc[j] += z*Ws[d*NC + j];
  }
  const float* Q = qf + ((size_t)(b*NC))*NPIX + n;
  #pragma unroll 2
  for(int d = 0; d < NC; d++){
    float z = Q[(size_t)d*NPIX];
    #pragma unroll
    for(int j = 0; j < NC; j++) acc[j] += z*Ws[(NC + d)*NC + j];
  }
  {
    float z = cfcb[(size_t)(br*NBATCH + b)*NPIX + n];
    #pragma unroll
    for(int j = 0; j < NC; j++) acc[j] += z*Ws[128*NC + j];
  }
  float* O = h1 + ((size_t)((br*NBATCH + b)*NC))*NPIX + n;
  #pragma unroll
  for(int j = 0; j < NC; j++) O[(size_t)j*NPIX] = acc[j];
}

// BN batch-stats: parallel partial sums + atomics, then tiny finalize
__global__ __launch_bounds__(256) void k_bnpart(const float* x, float* part, int C){
  __shared__ float rb[256];
  int c = blockIdx.x, br = blockIdx.y, b = blockIdx.z, tid = threadIdx.x;
  const float4* X = (const float4*)(x + ((size_t)((br*NBATCH + b)*C + c))*NPIX);
  float s = 0.f, ss = 0.f;
  for(int n = tid; n < NPIX/4; n += 256){
    float4 v = X[n];
    s  += v.x + v.y + v.z + v.w;
    ss += v.x*v.x + v.y*v.y + v.z*v.z + v.w*v.w;
  }
  float S  = blockSum256(s,  rb);
  float SS = blockSum256(ss, rb);
  if(tid == 0){
    atomicAdd(&part[(size_t)(br*C + c)*2],     S);
    atomicAdd(&part[(size_t)(br*C + c)*2 + 1], SS);
  }
}

__global__ void k_bnfin(const float* part, float* meanv, float* rstdv, int C){
  int i = blockIdx.x*64 + threadIdx.x;
  if(i < 2*C){
    float m = part[(size_t)i*2]     / (float)(NBATCH*NPIX);
    float v = part[(size_t)i*2 + 1] / (float)(NBATCH*NPIX) - m*m;
    meanv[i] = m;
    rstdv[i] = 1.0f / sqrtf(v + 1e-5f);
  }
}

__global__ __launch_bounds__(256) void k_conv2(const float* h1, const float* mean1, const float* rstd1,
                                               const float* g1, const float* be1,
                                               const float* w2, const float* b2, float* h2){
  __shared__ float Ws[NC*16];
  __shared__ float Pm[NC], Pr[NC], Pg[NC], Pb[NC];
  __shared__ float B2[16];
  int tid = threadIdx.x, b = blockIdx.y, br = blockIdx.z;
  for(int i = tid; i < NC*16; i += 256) Ws[i] = w2[i];
  if(tid < NC){ Pm[tid] = mean1[br*NC + tid]; Pr[tid] = rstd1[br*NC + tid]; Pg[tid] = g1[tid]; Pb[tid] = be1[tid]; }
  if(tid < 16) B2[tid] = b2[tid];
  __syncthreads();
  int n = blockIdx.x*256 + tid;
  const float* X = h1 + ((size_t)((br*NBATCH + b)*NC))*NPIX + n;
  float acc[16];
  #pragma unroll
  for(int j = 0; j < 16; j++) acc[j] = B2[j];
  for(int c = 0; c < NC; c++){
    float v = (X[(size_t)c*NPIX] - Pm[c])*Pr[c]*Pg[c] + Pb[c];
    v = fmaxf(v, 0.f);
    #pragma unroll
    for(int j = 0; j < 16; j++) acc[j] += v*Ws[c*16 + j];
  }
  float* O = h2 + ((size_t)((br*NBATCH + b)*16))*NPIX + n;
  #pragma unroll
  for(int j = 0; j < 16; j++) O[(size_t)j*NPIX] = acc[j];
}

__global__ __launch_bounds__(256) void k_gamma(const float* h2, const float* mean2, const float* rstd2,
                                               const float* g2, const float* be2,
                                               const float* w3, const float* b3,
                                               float* gamma, float* sumg){
  __shared__ float W3[16*4];
  __shared__ float Pm[16], Pr[16], Pg[16], Pb[16];
  __shared__ float B3[4];
  __shared__ float rb[256];
  int tid = threadIdx.x, b = blockIdx.y, br = blockIdx.z;
  if(tid < 64) W3[tid] = w3[tid];
  if(tid < 4)  B3[tid] = b3[tid];
  if(tid < 16){ Pm[tid] = mean2[br*16 + tid]; Pr[tid] = rstd2[br*16 + tid]; Pg[tid] = g2[tid]; Pb[tid] = be2[tid]; }
  __syncthreads();
  int n = blockIdx.x*256 + tid;
  const float* X = h2 + ((size_t)((br*NBATCH + b)*16))*NPIX + n;
  float l0 = B3[0], l1 = B3[1], l2 = B3[2], l3 = B3[3];
  #pragma unroll
  for(int c = 0; c < 16; c++){
    float v = (X[(size_t)c*NPIX] - Pm[c])*Pr[c]*Pg[c] + Pb[c];
    v = fmaxf(v, 0.f);
    l0 += v*W3[c*4 + 0]; l1 += v*W3[c*4 + 1]; l2 += v*W3[c*4 + 2]; l3 += v*W3[c*4 + 3];
  }
  float mx = fmaxf(fmaxf(l0, l1), fmaxf(l2, l3));
  float e0 = expf(l0 - mx), e1 = expf(l1 - mx), e2 = expf(l2 - mx), e3 = expf(l3 - mx);
  float inv = 1.0f / (e0 + e1 + e2 + e3);
  float q0 = e0*inv, q1 = e1*inv, q2 = e2*inv, q3 = e3*inv;
  float* G = gamma + ((size_t)((br*NBATCH + b)*NK))*NPIX + n;
  G[0] = q0; G[NPIX] = q1; G[2*NPIX] = q2; G[3*NPIX] = q3;
  int cb = br*NBATCH + b;
  float t;
  t = blockSum256(q0, rb); if(tid == 0) atomicAdd(&sumg[cb*4 + 0], t);
  t = blockSum256(q1, rb); if(tid == 0) atomicAdd(&sumg[cb*4 + 1], t);
  t = blockSum256(q2, rb); if(tid == 0) atomicAdd(&sumg[cb*4 + 2], t);
  t = blockSum256(q3, rb); if(tid == 0) atomicAdd(&sumg[cb*4 + 3], t);
}

// ---------------- GMM: mu ----------------

__global__ __launch_bounds__(256) void k_musum(const float* fgbg, const float* cfcb, const float* qf,
                                               const float* gamma, float* musum){
  __shared__ float rb[256];
  int d = blockIdx.x, b = blockIdx.y, br = blockIdx.z, tid = threadIdx.x;
  const float* Z = zrow(fgbg, cfcb, qf, br, b, d);
  const float* G = gamma + ((size_t)((br*NBATCH + b)*NK))*NPIX;
  float a0 = 0.f, a1 = 0.f, a2 = 0.f, a3 = 0.f;
  for(int n = tid; n < NPIX; n += 256){
    float z = Z[n];
    a0 += G[n]*z; a1 += G[NPIX + n]*z; a2 += G[2*NPIX + n]*z; a3 += G[3*NPIX + n]*z;
  }
  int cb = br*NBATCH + b;
  float t;
  t = blockSum256(a0, rb); if(tid == 0) musum[((size_t)(cb*4 + 0))*ND + d] = t;
  t = blockSum256(a1, rb); if(tid == 0) musum[((size_t)(cb*4 + 1))*ND + d] = t;
  t = blockSum256(a2, rb); if(tid == 0) musum[((size_t)(cb*4 + 2))*ND + d] = t;
  t = blockSum256(a3, rb); if(tid == 0) musum[((size_t)(cb*4 + 3))*ND + d] = t;
}

__global__ __launch_bounds__(256) void k_phimufin(const float* sumg, float* phi, float* logphi, float* mu){
  int tid = threadIdx.x;
  if(tid < NCOMBO){
    float sg = sumg[tid];
    float p = sg / (float)NPIX;
    phi[tid] = p;
    logphi[tid] = logf(p + 1e-12f);
  }
  for(int i = tid; i < NCOMBO*ND; i += 256){
    int c = i / ND;
    mu[i] = mu[i] / sumg[c];
  }
}

// ---------------- GMM: weighted second moment (upper triangle, tiles of 32) ----------------

__global__ __launch_bounds__(256) void k_cov(const float* fgbg, const float* cfcb, const float* qf,
                                             const float* gamma, float* Mpart){
  __shared__ float SD[32][34];
  __shared__ float SE[32][34];
  __shared__ __align__(16) float SG[32][4];
  int p = blockIdx.x, cbi = blockIdx.y, seg = blockIdx.z;
  int ti, tj;
  if(p < 4){ ti = 0; tj = p; } else if(p < 7){ ti = 1; tj = p - 3; }
  else if(p < 9){ ti = 2; tj = p - 5; } else { ti = 3; tj = 3; }
  int br = cbi >> 3, b = cbi & 7;
  int d0 = ti*32, e0 = tj*32;
  int tid = threadIdx.x, tx = tid & 15, ty = tid >> 4;
  float at[2][2] = {{0,0},{0,0}}, a0[2][2] = {{0,0},{0,0}}, a1[2][2] = {{0,0},{0,0}}, a2[2][2] = {{0,0},{0,0}};
  const float* G = gamma + ((size_t)(cbi*NK))*NPIX;
  int r = tid >> 3, jj = (tid & 7)*4;
  const float* Zd = zrow(fgbg, cfcb, qf, br, b, d0 + r);
  const float* Ze = zrow(fgbg, cfcb, qf, br, b, e0 + r);
  for(int nc = 0; nc < 72; nc++){
    int n0 = seg*2304 + nc*32;
    __syncthreads();
    {
      float4 v = *(const float4*)(Zd + n0 + jj);
      SD[jj][r] = v.x; SD[jj+1][r] = v.y; SD[jj+2][r] = v.z; SD[jj+3][r] = v.w;
      v = *(const float4*)(Ze + n0 + jj);
      SE[jj][r] = v.x; SE[jj+1][r] = v.y; SE[jj+2][r] = v.z; SE[jj+3][r] = v.w;
      if(tid < 128) SG[tid & 31][tid >> 5] = G[(size_t)(tid >> 5)*NPIX + n0 + (tid & 31)];
    }
    __syncthreads();
    #pragma unroll 4
    for(int nn = 0; nn < 32; nn++){
      float4 g4 = *(const float4*)(&SG[nn][0]);
      float zd0 = SD[nn][2*ty], zd1 = SD[nn][2*ty + 1];
      float ze0 = SE[nn][2*tx], ze1 = SE[nn][2*tx + 1];
      #pragma unroll
      for(int i = 0; i < 2; i++){
        float zd = i ? zd1 : zd0;
        #pragma unroll
        for(int j = 0; j < 2; j++){
          float ze = j ? ze1 : ze0;
          float pr = zd*ze;
          at[i][j] += pr;
          a0[i][j] += g4.x*pr;
          a1[i][j] += g4.y*pr;
          a2[i][j] += g4.z*pr;
        }
      }
    }
  }
  size_t slot0 = (size_t)(seg*64 + cbi*4);
  size_t st = (size_t)ND*PITCH;
  #pragma unroll
  for(int i = 0; i < 2; i++){
    #pragma unroll
    for(int j = 0; j < 2; j++){
      int d = d0 + 2*ty + i, e = e0 + 2*tx + j;
      if(e >= d){
        size_t o = (slot0*ND + d)*PITCH + e;
        Mpart[o]        = a0[i][j];
        Mpart[o + st]   = a1[i][j];
        Mpart[o + 2*st] = a2[i][j];
        Mpart[o + 3*st] = at[i][j];
      }
    }
  }
}

__global__ __launch_bounds__(256) void k_covstrip(const float* fgbg, const float* cfcb, const float* qf,
                                                  const float* gamma, float* Mpart){
  __shared__ float rb[256];
  int e = blockIdx.x, cb = blockIdx.y, seg = blockIdx.z, tid = threadIdx.x;
  int br = cb >> 3, b = cb & 7;
  const float* Ze = zrow(fgbg, cfcb, qf, br, b, e);
  const float* CF = cfcb + (size_t)cb*NPIX;
  const float* G  = gamma + ((size_t)(cb*NK))*NPIX;
  float at = 0.f, a0 = 0.f, a1 = 0.f, a2 = 0.f;
  int n0 = seg*2304;
  for(int n = n0 + tid; n < n0 + 2304; n += 256){
    float pr = Ze[n]*CF[n];
    at += pr; a0 += G[n]*pr; a1 += G[NPIX + n]*pr; a2 += G[2*NPIX + n]*pr;
  }
  size_t base = ((size_t)(seg*64 + cb*4)*ND + e)*PITCH + 128;
  size_t st = (size_t)ND*PITCH;
  float t;
  t = blockSum256(a0, rb); if(tid == 0) Mpart[base]        = t;
  t = blockSum256(a1, rb); if(tid == 0) Mpart[base + st]   = t;
  t = blockSum256(a2, rb); if(tid == 0) Mpart[base + 2*st] = t;
  t = blockSum256(at, rb); if(tid == 0) Mpart[base + 3*st] = t;
}

__global__ __launch_bounds__(192) void k_covfin(const float* Mpart, const float* sumg, const float* mu,
                                                float* covb){
  int i = blockIdx.x, c = blockIdx.y, j = threadIdx.x;
  if(j > i) return;
  int k = c & 3, cb4 = c & ~3;
  size_t st = (size_t)ND*PITCH;
  float s = 0.f;
  if(k < 3){
    #pragma unroll
    for(int sg = 0; sg < 4; sg++) s += Mpart[((size_t)(sg*64 + c)*ND + j)*PITCH + i];
  } else {
    #pragma unroll
    for(int sg = 0; sg < 4; sg++){
      size_t base = ((size_t)(sg*64 + cb4)*ND + j)*PITCH + i;
      s += Mpart[base + 3*st] - Mpart[base] - Mpart[base + st] - Mpart[base + 2*st];
    }
  }
  float sgv = sumg[c];
  float v = s/sgv - mu[(size_t)c*ND + i]*mu[(size_t)c*ND + j];
  if(i == j) v += 1e-6f;
  covb[((size_t)c*ND + i)*PITCH + j] = v;
}

// ---------------- Cholesky + logdet + sample + packed L^-1 (per combo) ----------------
// Packed layout: column e stored 4-aligned from row (e&~3) to 131, zero-filled
// above diagonal and beyond row 128. S(e) = sum_{e'<e} (132 - (e'&~3)).

__global__ __launch_bounds__(256) void k_cholinv(const float* covb, const float* muv, const float* phiv,
                                                 const float* nzf, const float* nzb,
                                                 float* Wpk, float* logdet, float* fs, float* dout){
  extern __shared__ float sh[];
  float* A    = sh;                    // ND x APITCH, lower triangle (raw V, then L)
  float* Wl   = sh + ND*APITCH;        // column-major: Wl[c*ND + i]
  float* rs   = Wl + ND*ND;            // 132: 1/L[j][j]
  float* cbuf = rs + 132;              // 2: double-buffered 1/diag
  __shared__ float rb[256];
  int c = blockIdx.x, tid = threadIdx.x;
  for(int idx = tid; idx < ND*ND; idx += 256){
    int i = idx / ND, j = idx - i*ND;
    if(j <= i) A[i*APITCH + j] = covb[((size_t)c*ND + i)*PITCH + j];
  }
  if(tid == 0) cbuf[0] = 1.0f / A[0];
  __syncthreads();
  // right-looking rank-1 updates on raw columns
  for(int j = 0; j < ND-1; j++){
    float invd = cbuf[j & 1];
    int i = j + 1 + tid;
    if(i < ND){
      float* Ai = A + (size_t)i*APITCH;
      float f = Ai[j] * invd;
      const float* Cj = A + j;
      #pragma unroll 4
      for(int k = j + 1; k <= i; k++) Ai[k] -= f * Cj[(size_t)k*APITCH];
      if(tid == 0) cbuf[(j + 1) & 1] = 1.0f / Ai[j + 1];
    }
    __syncthreads();
  }
  if(tid < ND) rs[tid] = 1.0f / sqrtf(A[(size_t)tid*APITCH + tid]);
  __syncthreads();
  for(int idx = tid; idx < ND*ND; idx += 256){
    int i = idx / ND, j = idx - i*ND;
    if(j <= i) A[(size_t)i*APITCH + j] *= rs[j];
  }
  __syncthreads();
  float ld = (tid < ND) ? logf(A[(size_t)tid*APITCH + tid]) : 0.f;
  float lsum = blockSum256(ld, rb);
  if(tid == 0) logdet[c] = 2.f*lsum;
  int br = c >> 5, b = (c >> 2) & 7, kk = c & 3;
  const float* nz = (br ? nzb : nzf) + (size_t)(b*NK + kk)*ND;
  if(tid < ND){
    const float* Ar = A + (size_t)tid*APITCH;
    float s = muv[(size_t)c*ND + tid];
    #pragma unroll 4
    for(int e = 0; e <= tid; e++) s += Ar[e]*nz[e];
    float v = s*phiv[c];
    fs[(size_t)c*ND + tid] = v;
    if(br == 0) dout[(size_t)kk*(NBATCH*ND) + (size_t)b*ND + tid] = v;
  }
  // W = L^{-1}: thread cc owns column cc, barrier-free forward substitution
  {
    int cc = tid;
    float* Wc = Wl + (size_t)cc*ND;
    for(int i = 0; i < ND; i++){
      if(cc <= i && cc < ND){
        float s = (i == cc) ? 1.f : 0.f;
        const float* Ar = A + (size_t)i*APITCH;
        #pragma unroll 4
        for(int k = cc; k < i; k++) s -= Ar[k]*Wc[k];
        Wc[i] = s * rs[i];
      }
    }
  }
  __syncthreads();
  // packed write: column e rows (e&~3)..131, zero-filled
  {
    float* dst0 = Wpk + (size_t)c*WPACK;
    int S = 0;
    for(int e = 0; e < 132; e++){
      int dstart = e & ~3;
      float* dst = dst0 + S;
      for(int i = dstart + tid; i < 132; i += 256){
        float v = 0.f;
        if(e < ND && i >= e && i < ND) v = Wl[(size_t)e*ND + i];
        dst[i - dstart] = v;
      }
      S += 132 - dstart;
    }
  }
}

// ---------------- quad = || W (z - mu) ||^2 per pixel (LDS-resident tiled GEMM) ----------------
// DF[132][68] + packed W fully in LDS; thread tile = 4 rows x 4 pixels, 2 d-sweeps,
// (P==1, ty==15) also covers rows 128..131 via an 8-row tile.
// NOTE: fat tile's A-quad (rows 124..127) must NOT read column e=128 (its packed
// storage starts at row 128) -> tail loop handles e in [d0+4, emax) B-quad-only.

#define QFMA(acc, wv) \
  acc.x += (wv)*x.x; acc.y += (wv)*x.y; acc.z += (wv)*x.z; acc.w += (wv)*x.w;

__global__ __launch_bounds__(256) void k_quad(const float* fgbg, const float* cfcb, const float* qf,
                                              const float* Wp, const float* mu, float* quad){
  extern __shared__ float sh[];
  float* DF = sh;             // [132][68]
  float* WL = sh + 132*68;    // WPACK
  float* QR = WL + WPACK;     // [16][68]
  int c = blockIdx.y;
  int br = c >> 5, b = (c >> 2) & 7;
  int n0 = blockIdx.x*64;
  int tid = threadIdx.x;
  // stage DF = z - mu (pad rows 129..131 = 0)
  for(int idx = tid; idx < 132*16; idx += 256){
    int r = idx >> 4, c4 = (idx & 15)*4;
    float4 v = make_float4(0.f, 0.f, 0.f, 0.f);
    if(r < ND){
      const float* Zr = zrow(fgbg, cfcb, qf, br, b, r);
      v = *(const float4*)(Zr + n0 + c4);
      float m = mu[(size_t)c*ND + r];
      v.x -= m; v.y -= m; v.z -= m; v.w -= m;
    }
    *(float4*)&DF[r*68 + c4] = v;
  }
  // stage packed W
  {
    const float4* Wg4 = (const float4*)(Wp + (size_t)c*WPACK);
    float4* WL4 = (float4*)WL;
    for(int idx = tid; idx < WPACK/4; idx += 256) WL4[idx] = Wg4[idx];
  }
  __syncthreads();
  int tx = tid & 15, ty = tid >> 4;
  int p0 = 4*tx;
  float4 q = make_float4(0.f, 0.f, 0.f, 0.f);
  #pragma unroll
  for(int P = 0; P < 2; P++){
    int d0 = 4*(16*P + ty);
    bool fat = (P == 1) && (ty == 15);
    int eA   = min(d0 + 4, ND);             // columns feeding the A-quad rows d0..d0+3
    int emax = fat ? ND : eA;               // fat tile also needs columns for rows d0+4..d0+7
    float4 A0 = make_float4(0,0,0,0), A1 = A0, A2 = A0, A3 = A0;
    float4 B0 = A0, B1 = A0, B2 = A0, B3 = A0;
    for(int e = 0; e < eA; e++){
      int a = e >> 2;
      int base = 132*e - 8*a*(a-1) - 4*(e & 3)*a + d0 - 4*a;   // S(e) + d0 - dstart
      float4 x = *(const float4*)&DF[e*68 + p0];
      float4 w = *(const float4*)&WL[base];
      QFMA(A0, w.x) QFMA(A1, w.y) QFMA(A2, w.z) QFMA(A3, w.w)
      if(fat){
        float4 w2 = *(const float4*)&WL[base + 4];
        QFMA(B0, w2.x) QFMA(B1, w2.y) QFMA(B2, w2.z) QFMA(B3, w2.w)
      }
    }
    if(fat){
      for(int e = eA; e < emax; e++){       // e == 128 only: B rows 128..131, dstart==128
        int a = e >> 2;
        int base = 132*e - 8*a*(a-1) - 4*(e & 3)*a + d0 + 4 - 4*a;  // S(e) + (d0+4) - dstart
        float4 x = *(const float4*)&DF[e*68 + p0];
        float4 w2 = *(const float4*)&WL[base];
        QFMA(B0, w2.x) QFMA(B1, w2.y) QFMA(B2, w2.z) QFMA(B3, w2.w)
      }
    }
    q.x += A0.x*A0.x + A1.x*A1.x + A2.x*A2.x + A3.x*A3.x;
    q.y += A0.y*A0.y + A1.y*A1.y + A2.y*A2.y + A3.y*A3.y;
    q.z += A0.z*A0.z + A1.z*A1.z + A2.z*A2.z + A3.z*A3.z;
    q.w += A0.w*A0.w + A1.w*A1.w + A2.w*A2.w + A3.w*A3.w;
    if(fat){
      q.x += B0.x*B0.x + B1.x*B1.x + B2.x*B2.x + B3.x*B3.x;
      q.y += B0.y*B0.y + B1.y*B1.y + B2.y*B2.y + B3.y*B3.y;
      q.z += B0.z*B0.z + B1.z*B1.z + B2.z*B2.z + B3.z*B3.z;
      q.w += B0.w*B0.w + B1.w*B1.w + B2.w*B2.w + B3.w*B3.w;
    }
  }
  *(float4*)&QR[ty*68 + p0] = q;
  __syncthreads();
  if(tid < 64){
    float s = 0.f;
    #pragma unroll
    for(int t = 0; t < 16; t++) s += QR[t*68 + tid];
    quad[(size_t)c*NPIX + n0 + tid] = s;
  }
}

// ---------------- energy ----------------

__global__ __launch_bounds__(256) void k_energy(const float* quad, const float* logdet, const float* logphi,
                                                float* eacc){
  __shared__ float rb[256];
  int tid = threadIdx.x;
  int n = blockIdx.x*256 + tid, b = blockIdx.y, br = blockIdx.z;
  int c0 = (br*NBATCH + b)*NK;
  const float C0 = 118.54307078340277f;  // 0.5 * 129 * ln(2*pi)
  float l0 = -0.5f*quad[(size_t)(c0 + 0)*NPIX + n] - 0.5f*logdet[c0 + 0] - C0 + logphi[c0 + 0];
  float l1 = -0.5f*quad[(size_t)(c0 + 1)*NPIX + n] - 0.5f*logdet[c0 + 1] - C0 + logphi[c0 + 1];
  float l2 = -0.5f*quad[(size_t)(c0 + 2)*NPIX + n] - 0.5f*logdet[c0 + 2] - C0 + logphi[c0 + 2];
  float l3 = -0.5f*quad[(size_t)(c0 + 3)*NPIX + n] - 0.5f*logdet[c0 + 3] - C0 + logphi[c0 + 3];
  float mx = fmaxf(fmaxf(l0, l1), fmaxf(l2, l3));
  float lse = mx + logf(expf(l0 - mx) + expf(l1 - mx) + expf(l2 - mx) + expf(l3 - mx));
  float t = blockSum256(lse, rb);
  if(tid == 0) atomicAdd(&eacc[br], t);
}

__global__ void k_fin(const float* eacc, float* dout){
  int t = threadIdx.x;
  if(t < 2) dout[151584 + t] = -eacc[t] / (float)(NBATCH*NPIX);
}

// ---------------- discriminative prob map ----------------

__global__ __launch_bounds__(256) void k_prob(const float* fgbg, const float* cfcb, const float* qf,
                                              const float* fs, float* dout){
  __shared__ float MC[8][132];
  int b = blockIdx.y, tid = threadIdx.x;
  for(int idx = tid; idx < 8*ND; idx += 256){
    int m = idx / ND, d = idx - m*ND;
    int br = m >> 2, kk = m & 3;
    MC[m][d] = fs[(size_t)((br*NBATCH + b)*NK + kk)*ND + d];
  }
  __syncthreads();
  int n = blockIdx.x*256 + tid;
  float a[8] = {0,0,0,0,0,0,0,0};
  const float* Z0 = fgbg + ((size_t)(b*NC))*NPIX + n;
  for(int d = 0; d < NC; d++){
    float z = Z0[(size_t)d*NPIX];
    #pragma unroll
    for(int m = 0; m < 8; m++) a[m] += z*MC[m][d];
  }
  const float* Q = qf + ((size_t)(b*NC))*NPIX + n;
  for(int d = 0; d < NC; d++){
    float z = Q[(size_t)d*NPIX];
    #pragma unroll
    for(int m = 0; m < 8; m++) a[m] += z*MC[m][NC + d];
  }
  {
    float z = cfcb[(size_t)b*NPIX + n];
    #pragma unroll
    for(int m = 0; m < 8; m++) a[m] += z*MC[m][128];
  }
  float mx = a[0];
  #pragma unroll
  for(int m = 1; m < 8; m++) mx = fmaxf(mx, a[m]);
  float e[8]; float ssum = 0.f;
  #pragma unroll
  for(int m = 0; m < 8; m++){ e[m] = expf(a[m] - mx); ssum += e[m]; }
  float inv = 1.f/ssum;
  float Pf = (e[0] + e[1] + e[2] + e[3])*inv;
  float Pb = (e[4] + e[5] + e[6] + e[7])*inv;
  dout[4128 + ((size_t)(b*2))*NPIX + n]     = Pb;
  dout[4128 + ((size_t)(b*2 + 1))*NPIX + n] = Pf;
}

// ---------------- launcher ----------------

extern "C" void kernel_launch(void* const* d_in, const int* in_sizes, int n_in,
                              void* d_out, int out_size, void* d_ws, size_t ws_size,
                              hipStream_t stream){
  const float* sf  = (const float*)d_in[0];
  const float* smk = (const float*)d_in[1];
  const float* qfp = (const float*)d_in[2];
  const float* w1  = (const float*)d_in[3];
  const float* b1  = (const float*)d_in[4];
  const float* g1  = (const float*)d_in[5];
  const float* be1 = (const float*)d_in[6];
  const float* w2  = (const float*)d_in[7];
  const float* b2  = (const float*)d_in[8];
  const float* g2  = (const float*)d_in[9];
  const float* be2 = (const float*)d_in[10];
  const float* w3  = (const float*)d_in[11];
  const float* b3  = (const float*)d_in[12];
  const float* nzf = (const float*)d_in[13];
  const float* nzb = (const float*)d_in[14];
  float* out = (float*)d_out;
  float* W   = (float*)d_ws;

  constexpr size_t OFF_FGBG  = 0;
  constexpr size_t SZ_FGBG   = (size_t)2*NBATCH*NC*NPIX;
  constexpr size_t OFF_CFCB  = OFF_FGBG + SZ_FGBG;
  constexpr size_t SZ_CFCB   = (size_t)2*NBATCH*NPIX;
  constexpr size_t OFF_H1    = OFF_CFCB + SZ_CFCB;
  constexpr size_t SZ_H1     = (size_t)2*NBATCH*NC*NPIX;
  constexpr size_t OFF_MPART = OFF_H1;
  constexpr size_t SZ_MPART  = (size_t)4*NCOMBO*ND*PITCH;
  constexpr size_t OFF_COVB  = OFF_H1 + SZ_MPART;
  constexpr size_t OFF_H2    = OFF_H1 + SZ_H1;
  constexpr size_t SZ_H2     = (size_t)2*NBATCH*16*NPIX;
  constexpr size_t OFF_W     = OFF_H2;              // packed W^-1 reuses h2
  constexpr size_t OFF_GAMMA = OFF_H2 + SZ_H2;
  constexpr size_t SZ_GAMMA  = (size_t)2*NBATCH*NK*NPIX;
  constexpr size_t OFF_QUAD  = OFF_GAMMA + SZ_GAMMA;
  constexpr size_t SZ_QUAD   = SZ_GAMMA;
  constexpr size_t OFF_SC    = OFF_QUAD + SZ_QUAD;

  float* fgbg  = W + OFF_FGBG;
  float* cfcb  = W + OFF_CFCB;
  float* h1    = W + OFF_H1;
  float* h2    = W + OFF_H2;
  float* gamma = W + OFF_GAMMA;
  float* quad  = W + OFF_QUAD;
  float* Mpart = W + OFF_MPART;
  float* covb  = W + OFF_COVB;
  float* Wpack = W + OFF_W;
  float* sc    = W + OFF_SC;
  float* mean1 = sc;          float* rstd1  = sc + 128;
  float* mean2 = sc + 256;    float* rstd2  = sc + 288;
  float* sumg  = sc + 320;    float* eacc   = sc + 384;   // zero region: sumg..bnp2 (386 floats)
  float* bnp1  = sc + 386;    float* bnp2   = sc + 642;
  float* phi   = sc + 706;    float* logphi = sc + 770;
  float* mu    = sc + 834;
  float* logdetv = sc + 9090;
  float* fsv   = sc + 9154;

  hipMemsetAsync(sumg, 0, 386*sizeof(float), stream);

  k_prep   <<<dim3(36, 8),      256, 0, stream>>>(sf, smk, qfp, fgbg, cfcb);
  k_conv1  <<<dim3(36, 8, 2),   256, 0, stream>>>(fgbg, cfcb, qfp, w1, b1, h1);
  k_bnpart <<<dim3(64, 2, 8),   256, 0, stream>>>(h1, bnp1, 64);
  k_bnfin  <<<2, 64,                0, stream>>>(bnp1, mean1, rstd1, 64);
  k_conv2  <<<dim3(36, 8, 2),   256, 0, stream>>>(h1, mean1, rstd1, g1, be1, w2, b2, h2);
  k_bnpart <<<dim3(16, 2, 8),   256, 0, stream>>>(h2, bnp2, 16);
  k_bnfin  <<<1, 64,                0, stream>>>(bnp2, mean2, rstd2, 16);
  k_gamma  <<<dim3(36, 8, 2),   256, 0, stream>>>(h2, mean2, rstd2, g2, be2, w3, b3, gamma, sumg);
  k_musum  <<<dim3(129, 8, 2),  256, 0, stream>>>(fgbg, cfcb, qfp, gamma, mu);
  k_phimufin<<<1,               256, 0, stream>>>(sumg, phi, logphi, mu);
  k_cov    <<<dim3(10, 16, 4),  256, 0, stream>>>(fgbg, cfcb, qfp, gamma, Mpart);
  k_covstrip<<<dim3(129, 16, 4),256, 0, stream>>>(fgbg, cfcb, qfp, gamma, Mpart);
  k_covfin <<<dim3(129, 64),    192, 0, stream>>>(Mpart, sumg, mu, covb);
  k_cholinv<<<64, 256, (ND*APITCH + ND*ND + 132 + 4)*sizeof(float), stream>>>(covb, mu, phi, nzf, nzb,
                                                                              Wpack, logdetv, fsv, out);
  k_quad   <<<dim3(144, 64),    256, (132*68 + WPACK + 16*68)*sizeof(float), stream>>>(
                                     fgbg, cfcb, qfp, Wpack, mu, quad);
  k_energy <<<dim3(36, 8, 2),   256, 0, stream>>>(quad, logdetv, logphi, eacc);
  k_prob   <<<dim3(36, 8),      256, 0, stream>>>(fgbg, cfcb, qfp, fsv, out);
  k_fin    <<<1, 64, 0, stream>>>(eacc, out);
}

// Round 8
// 1394.209 us; speedup vs baseline: 1.4431x; 1.0593x over previous
//
#include <hip/hip_runtime.h>
#include <math.h>

#define NPIX 9216
#define NBATCH 8
#define NC 64
#define ND 129
#define NK 4
#define NCOMBO 64   // 2 branches * 8 batch * 4 k
#define PITCH 132   // row pitch for 129-wide matrices in global
#define APITCH 131  // LDS pitch for cholesky (131%32=3 -> bank-clean column access)
#define WPACK 8976  // packed triangular W floats per combo (4-aligned columns)

// ---------------- helpers ----------------

__device__ __forceinline__ const float* zrow(const float* fgbg, const float* cfcb, const float* qf,
                                             int br, int b, int d){
  if(d < NC)        return fgbg + ((size_t)((br*NBATCH + b)*NC + d))*NPIX;
  else if(d < 2*NC) return qf   + ((size_t)(b*NC + (d - NC)))*NPIX;
  else              return cfcb + (size_t)(br*NBATCH + b)*NPIX;
}

__device__ __forceinline__ float blockSum256(float v, float* rb){
  int tid = threadIdx.x;
  rb[tid] = v; __syncthreads();
  #pragma unroll
  for(int s = 128; s > 0; s >>= 1){
    if(tid < s) rb[tid] += rb[tid + s];
    __syncthreads();
  }
  float r = rb[0]; __syncthreads();
  return r;
}

// ---------------- stage 1: fg/bg/cosine ----------------

__global__ __launch_bounds__(256) void k_prep(const float* sf, const float* smk, const float* qf,
                                              float* fgbg, float* cfcb){
  int tid = threadIdx.x, b = blockIdx.y;
  int n = blockIdx.x*256 + tid;
  float m = smk[(size_t)b*NPIX + n];
  const float* S = sf + ((size_t)(b*NC))*NPIX + n;
  const float* Q = qf + ((size_t)(b*NC))*NPIX + n;
  float* FG = fgbg + ((size_t)(b*NC))*NPIX + n;
  float* BG = fgbg + ((size_t)((NBATCH + b)*NC))*NPIX + n;
  float df = 0.f, db = 0.f, nf = 0.f, nb_ = 0.f, nq = 0.f;
  #pragma unroll 4
  for(int c = 0; c < NC; c++){
    float s = S[(size_t)c*NPIX], q = Q[(size_t)c*NPIX];
    float f = s*m, g = s - f;
    FG[(size_t)c*NPIX] = f; BG[(size_t)c*NPIX] = g;
    df += f*q; db += g*q; nf += f*f; nb_ += g*g; nq += q*q;
  }
  float rq = fmaxf(sqrtf(nq), 1e-8f);
  cfcb[(size_t)b*NPIX + n]            = df / (fmaxf(sqrtf(nf),  1e-8f) * rq);
  cfcb[(size_t)(NBATCH + b)*NPIX + n] = db / (fmaxf(sqrtf(nb_), 1e-8f) * rq);
}

// ---------------- estimator ----------------

__global__ __launch_bounds__(256) void k_conv1(const float* fgbg, const float* cfcb, const float* qf,
                                               const float* w1, const float* b1, float* h1){
  __shared__ float Ws[ND*NC];
  __shared__ float B1[NC];
  int tid = threadIdx.x, b = blockIdx.y, br = blockIdx.z;
  for(int i = tid; i < ND*NC; i += 256) Ws[i] = w1[i];
  if(tid < NC) B1[tid] = b1[tid];
  __syncthreads();
  int n = blockIdx.x*256 + tid;
  float acc[NC];
  #pragma unroll
  for(int j = 0; j < NC; j++) acc[j] = B1[j];
  const float* Z0 = fgbg + ((size_t)((br*NBATCH + b)*NC))*NPIX + n;
  #pragma unroll 2
  for(int d = 0; d < NC; d++){
    float z = Z0[(size_t)d*NPIX];
    #pragma unroll
    for(int j = 0; j < NC; j++) acc[j] += z*Ws[d*NC + j];
  }
  const float* Q = qf + ((size_t)(b*NC))*NPIX + n;
  #pragma unroll 2
  for(int d = 0; d < NC; d++){
    float z = Q[(size_t)d*NPIX];
    #pragma unroll
    for(int j = 0; j < NC; j++) acc[j] += z*Ws[(NC + d)*NC + j];
  }
  {
    float z = cfcb[(size_t)(br*NBATCH + b)*NPIX + n];
    #pragma unroll
    for(int j = 0; j < NC; j++) acc[j] += z*Ws[128*NC + j];
  }
  float* O = h1 + ((size_t)((br*NBATCH + b)*NC))*NPIX + n;
  #pragma unroll
  for(int j = 0; j < NC; j++) O[(size_t)j*NPIX] = acc[j];
}

// BN batch-stats: parallel partial sums + atomics, then tiny finalize
__global__ __launch_bounds__(256) void k_bnpart(const float* x, float* part, int C){
  __shared__ float rb[256];
  int c = blockIdx.x, br = blockIdx.y, b = blockIdx.z, tid = threadIdx.x;
  const float4* X = (const float4*)(x + ((size_t)((br*NBATCH + b)*C + c))*NPIX);
  float s = 0.f, ss = 0.f;
  for(int n = tid; n < NPIX/4; n += 256){
    float4 v = X[n];
    s  += v.x + v.y + v.z + v.w;
    ss += v.x*v.x + v.y*v.y + v.z*v.z + v.w*v.w;
  }
  float S  = blockSum256(s,  rb);
  float SS = blockSum256(ss, rb);
  if(tid == 0){
    atomicAdd(&part[(size_t)(br*C + c)*2],     S);
    atomicAdd(&part[(size_t)(br*C + c)*2 + 1], SS);
  }
}

__global__ void k_bnfin(const float* part, float* meanv, float* rstdv, int C){
  int i = blockIdx.x*64 + threadIdx.x;
  if(i < 2*C){
    float m = part[(size_t)i*2]     / (float)(NBATCH*NPIX);
    float v = part[(size_t)i*2 + 1] / (float)(NBATCH*NPIX) - m*m;
    meanv[i] = m;
    rstdv[i] = 1.0f / sqrtf(v + 1e-5f);
  }
}

__global__ __launch_bounds__(256) void k_conv2(const float* h1, const float* mean1, const float* rstd1,
                                               const float* g1, const float* be1,
                                               const float* w2, const float* b2, float* h2){
  __shared__ float Ws[NC*16];
  __shared__ float Pm[NC], Pr[NC], Pg[NC], Pb[NC];
  __shared__ float B2[16];
  int tid = threadIdx.x, b = blockIdx.y, br = blockIdx.z;
  for(int i = tid; i < NC*16; i += 256) Ws[i] = w2[i];
  if(tid < NC){ Pm[tid] = mean1[br*NC + tid]; Pr[tid] = rstd1[br*NC + tid]; Pg[tid] = g1[tid]; Pb[tid] = be1[tid]; }
  if(tid < 16) B2[tid] = b2[tid];
  __syncthreads();
  int n = blockIdx.x*256 + tid;
  const float* X = h1 + ((size_t)((br*NBATCH + b)*NC))*NPIX + n;
  float acc[16];
  #pragma unroll
  for(int j = 0; j < 16; j++) acc[j] = B2[j];
  for(int c = 0; c < NC; c++){
    float v = (X[(size_t)c*NPIX] - Pm[c])*Pr[c]*Pg[c] + Pb[c];
    v = fmaxf(v, 0.f);
    #pragma unroll
    for(int j = 0; j < 16; j++) acc[j] += v*Ws[c*16 + j];
  }
  float* O = h2 + ((size_t)((br*NBATCH + b)*16))*NPIX + n;
  #pragma unroll
  for(int j = 0; j < 16; j++) O[(size_t)j*NPIX] = acc[j];
}

__global__ __launch_bounds__(256) void k_gamma(const float* h2, const float* mean2, const float* rstd2,
                                               const float* g2, const float* be2,
                                               const float* w3, const float* b3,
                                               float* gamma, float* sumg){
  __shared__ float W3[16*4];
  __shared__ float Pm[16], Pr[16], Pg[16], Pb[16];
  __shared__ float B3[4];
  __shared__ float rb[256];
  int tid = threadIdx.x, b = blockIdx.y, br = blockIdx.z;
  if(tid < 64) W3[tid] = w3[tid];
  if(tid < 4)  B3[tid] = b3[tid];
  if(tid < 16){ Pm[tid] = mean2[br*16 + tid]; Pr[tid] = rstd2[br*16 + tid]; Pg[tid] = g2[tid]; Pb[tid] = be2[tid]; }
  __syncthreads();
  int n = blockIdx.x*256 + tid;
  const float* X = h2 + ((size_t)((br*NBATCH + b)*16))*NPIX + n;
  float l0 = B3[0], l1 = B3[1], l2 = B3[2], l3 = B3[3];
  #pragma unroll
  for(int c = 0; c < 16; c++){
    float v = (X[(size_t)c*NPIX] - Pm[c])*Pr[c]*Pg[c] + Pb[c];
    v = fmaxf(v, 0.f);
    l0 += v*W3[c*4 + 0]; l1 += v*W3[c*4 + 1]; l2 += v*W3[c*4 + 2]; l3 += v*W3[c*4 + 3];
  }
  float mx = fmaxf(fmaxf(l0, l1), fmaxf(l2, l3));
  float e0 = expf(l0 - mx), e1 = expf(l1 - mx), e2 = expf(l2 - mx), e3 = expf(l3 - mx);
  float inv = 1.0f / (e0 + e1 + e2 + e3);
  float q0 = e0*inv, q1 = e1*inv, q2 = e2*inv, q3 = e3*inv;
  float* G = gamma + ((size_t)((br*NBATCH + b)*NK))*NPIX + n;
  G[0] = q0; G[NPIX] = q1; G[2*NPIX] = q2; G[3*NPIX] = q3;
  int cb = br*NBATCH + b;
  float t;
  t = blockSum256(q0, rb); if(tid == 0) atomicAdd(&sumg[cb*4 + 0], t);
  t = blockSum256(q1, rb); if(tid == 0) atomicAdd(&sumg[cb*4 + 1], t);
  t = blockSum256(q2, rb); if(tid == 0) atomicAdd(&sumg[cb*4 + 2], t);
  t = blockSum256(q3, rb); if(tid == 0) atomicAdd(&sumg[cb*4 + 3], t);
}

// ---------------- GMM: mu ----------------

__global__ __launch_bounds__(256) void k_musum(const float* fgbg, const float* cfcb, const float* qf,
                                               const float* gamma, float* musum){
  __shared__ float rb[256];
  int d = blockIdx.x, b = blockIdx.y, br = blockIdx.z, tid = threadIdx.x;
  const float* Z = zrow(fgbg, cfcb, qf, br, b, d);
  const float* G = gamma + ((size_t)((br*NBATCH + b)*NK))*NPIX;
  float a0 = 0.f, a1 = 0.f, a2 = 0.f, a3 = 0.f;
  for(int n = tid; n < NPIX; n += 256){
    float z = Z[n];
    a0 += G[n]*z; a1 += G[NPIX + n]*z; a2 += G[2*NPIX + n]*z; a3 += G[3*NPIX + n]*z;
  }
  int cb = br*NBATCH + b;
  float t;
  t = blockSum256(a0, rb); if(tid == 0) musum[((size_t)(cb*4 + 0))*ND + d] = t;
  t = blockSum256(a1, rb); if(tid == 0) musum[((size_t)(cb*4 + 1))*ND + d] = t;
  t = blockSum256(a2, rb); if(tid == 0) musum[((size_t)(cb*4 + 2))*ND + d] = t;
  t = blockSum256(a3, rb); if(tid == 0) musum[((size_t)(cb*4 + 3))*ND + d] = t;
}

__global__ __launch_bounds__(256) void k_phimufin(const float* sumg, float* phi, float* logphi, float* mu){
  int tid = threadIdx.x;
  if(tid < NCOMBO){
    float sg = sumg[tid];
    float p = sg / (float)NPIX;
    phi[tid] = p;
    logphi[tid] = logf(p + 1e-12f);
  }
  for(int i = tid; i < NCOMBO*ND; i += 256){
    int c = i / ND;
    mu[i] = mu[i] / sumg[c];
  }
}

// ---------------- GMM: weighted second moment (upper triangle, tiles of 32) ----------------

__global__ __launch_bounds__(256) void k_cov(const float* fgbg, const float* cfcb, const float* qf,
                                             const float* gamma, float* Mpart){
  __shared__ float SD[32][34];
  __shared__ float SE[32][34];
  __shared__ __align__(16) float SG[32][4];
  int p = blockIdx.x, cbi = blockIdx.y, seg = blockIdx.z;
  int ti, tj;
  if(p < 4){ ti = 0; tj = p; } else if(p < 7){ ti = 1; tj = p - 3; }
  else if(p < 9){ ti = 2; tj = p - 5; } else { ti = 3; tj = 3; }
  int br = cbi >> 3, b = cbi & 7;
  int d0 = ti*32, e0 = tj*32;
  int tid = threadIdx.x, tx = tid & 15, ty = tid >> 4;
  float at[2][2] = {{0,0},{0,0}}, a0[2][2] = {{0,0},{0,0}}, a1[2][2] = {{0,0},{0,0}}, a2[2][2] = {{0,0},{0,0}};
  const float* G = gamma + ((size_t)(cbi*NK))*NPIX;
  int r = tid >> 3, jj = (tid & 7)*4;
  const float* Zd = zrow(fgbg, cfcb, qf, br, b, d0 + r);
  const float* Ze = zrow(fgbg, cfcb, qf, br, b, e0 + r);
  for(int nc = 0; nc < 72; nc++){
    int n0 = seg*2304 + nc*32;
    __syncthreads();
    {
      float4 v = *(const float4*)(Zd + n0 + jj);
      SD[jj][r] = v.x; SD[jj+1][r] = v.y; SD[jj+2][r] = v.z; SD[jj+3][r] = v.w;
      v = *(const float4*)(Ze + n0 + jj);
      SE[jj][r] = v.x; SE[jj+1][r] = v.y; SE[jj+2][r] = v.z; SE[jj+3][r] = v.w;
      if(tid < 128) SG[tid & 31][tid >> 5] = G[(size_t)(tid >> 5)*NPIX + n0 + (tid & 31)];
    }
    __syncthreads();
    #pragma unroll 4
    for(int nn = 0; nn < 32; nn++){
      float4 g4 = *(const float4*)(&SG[nn][0]);
      float zd0 = SD[nn][2*ty], zd1 = SD[nn][2*ty + 1];
      float ze0 = SE[nn][2*tx], ze1 = SE[nn][2*tx + 1];
      #pragma unroll
      for(int i = 0; i < 2; i++){
        float zd = i ? zd1 : zd0;
        #pragma unroll
        for(int j = 0; j < 2; j++){
          float ze = j ? ze1 : ze0;
          float pr = zd*ze;
          at[i][j] += pr;
          a0[i][j] += g4.x*pr;
          a1[i][j] += g4.y*pr;
          a2[i][j] += g4.z*pr;
        }
      }
    }
  }
  size_t slot0 = (size_t)(seg*64 + cbi*4);
  size_t st = (size_t)ND*PITCH;
  #pragma unroll
  for(int i = 0; i < 2; i++){
    #pragma unroll
    for(int j = 0; j < 2; j++){
      int d = d0 + 2*ty + i, e = e0 + 2*tx + j;
      if(e >= d){
        size_t o = (slot0*ND + d)*PITCH + e;
        Mpart[o]        = a0[i][j];
        Mpart[o + st]   = a1[i][j];
        Mpart[o + 2*st] = a2[i][j];
        Mpart[o + 3*st] = at[i][j];
      }
    }
  }
}

__global__ __launch_bounds__(256) void k_covstrip(const float* fgbg, const float* cfcb, const float* qf,
                                                  const float* gamma, float* Mpart){
  __shared__ float rb[256];
  int e = blockIdx.x, cb = blockIdx.y, seg = blockIdx.z, tid = threadIdx.x;
  int br = cb >> 3, b = cb & 7;
  const float* Ze = zrow(fgbg, cfcb, qf, br, b, e);
  const float* CF = cfcb + (size_t)cb*NPIX;
  const float* G  = gamma + ((size_t)(cb*NK))*NPIX;
  float at = 0.f, a0 = 0.f, a1 = 0.f, a2 = 0.f;
  int n0 = seg*2304;
  for(int n = n0 + tid; n < n0 + 2304; n += 256){
    float pr = Ze[n]*CF[n];
    at += pr; a0 += G[n]*pr; a1 += G[NPIX + n]*pr; a2 += G[2*NPIX + n]*pr;
  }
  size_t base = ((size_t)(seg*64 + cb*4)*ND + e)*PITCH + 128;
  size_t st = (size_t)ND*PITCH;
  float t;
  t = blockSum256(a0, rb); if(tid == 0) Mpart[base]        = t;
  t = blockSum256(a1, rb); if(tid == 0) Mpart[base + st]   = t;
  t = blockSum256(a2, rb); if(tid == 0) Mpart[base + 2*st] = t;
  t = blockSum256(at, rb); if(tid == 0) Mpart[base + 3*st] = t;
}

__global__ __launch_bounds__(192) void k_covfin(const float* Mpart, const float* sumg, const float* mu,
                                                float* covb){
  int i = blockIdx.x, c = blockIdx.y, j = threadIdx.x;
  if(j > i) return;
  int k = c & 3, cb4 = c & ~3;
  size_t st = (size_t)ND*PITCH;
  float s = 0.f;
  if(k < 3){
    #pragma unroll
    for(int sg = 0; sg < 4; sg++) s += Mpart[((size_t)(sg*64 + c)*ND + j)*PITCH + i];
  } else {
    #pragma unroll
    for(int sg = 0; sg < 4; sg++){
      size_t base = ((size_t)(sg*64 + cb4)*ND + j)*PITCH + i;
      s += Mpart[base + 3*st] - Mpart[base] - Mpart[base + st] - Mpart[base + 2*st];
    }
  }
  float sgv = sumg[c];
  float v = s/sgv - mu[(size_t)c*ND + i]*mu[(size_t)c*ND + j];
  if(i == j) v += 1e-6f;
  covb[((size_t)c*ND + i)*PITCH + j] = v;
}

// ---------------- Cholesky + logdet + sample + packed L^-1 (per combo) ----------------
// Packed layout: column e stored 4-aligned from row (e&~3) to 131, zero-filled
// above diagonal and beyond row 128. S(e) = sum_{e'<e} (132 - (e'&~3)).

__global__ __launch_bounds__(256) void k_cholinv(const float* covb, const float* muv, const float* phiv,
                                                 const float* nzf, const float* nzb,
                                                 float* Wpk, float* logdet, float* fs, float* dout){
  extern __shared__ float sh[];
  float* A    = sh;                    // ND x APITCH, lower triangle (raw V, then L)
  float* Wl   = sh + ND*APITCH;        // column-major: Wl[c*ND + i]
  float* rs   = Wl + ND*ND;            // 132: 1/L[j][j]
  float* cbuf = rs + 132;              // 2: double-buffered 1/diag
  __shared__ float rb[256];
  int c = blockIdx.x, tid = threadIdx.x;
  for(int idx = tid; idx < ND*ND; idx += 256){
    int i = idx / ND, j = idx - i*ND;
    if(j <= i) A[i*APITCH + j] = covb[((size_t)c*ND + i)*PITCH + j];
  }
  if(tid == 0) cbuf[0] = 1.0f / A[0];
  __syncthreads();
  // right-looking rank-1 updates on raw columns
  for(int j = 0; j < ND-1; j++){
    float invd = cbuf[j & 1];
    int i = j + 1 + tid;
    if(i < ND){
      float* Ai = A + (size_t)i*APITCH;
      float f = Ai[j] * invd;
      const float* Cj = A + j;
      #pragma unroll 4
      for(int k = j + 1; k <= i; k++) Ai[k] -= f * Cj[(size_t)k*APITCH];
      if(tid == 0) cbuf[(j + 1) & 1] = 1.0f / Ai[j + 1];
    }
    __syncthreads();
  }
  if(tid < ND) rs[tid] = 1.0f / sqrtf(A[(size_t)tid*APITCH + tid]);
  __syncthreads();
  for(int idx = tid; idx < ND*ND; idx += 256){
    int i = idx / ND, j = idx - i*ND;
    if(j <= i) A[(size_t)i*APITCH + j] *= rs[j];
  }
  __syncthreads();
  float ld = (tid < ND) ? logf(A[(size_t)tid*APITCH + tid]) : 0.f;
  float lsum = blockSum256(ld, rb);
  if(tid == 0) logdet[c] = 2.f*lsum;
  int br = c >> 5, b = (c >> 2) & 7, kk = c & 3;
  const float* nz = (br ? nzb : nzf) + (size_t)(b*NK + kk)*ND;
  if(tid < ND){
    const float* Ar = A + (size_t)tid*APITCH;
    float s = muv[(size_t)c*ND + tid];
    #pragma unroll 4
    for(int e = 0; e <= tid; e++) s += Ar[e]*nz[e];
    float v = s*phiv[c];
    fs[(size_t)c*ND + tid] = v;
    if(br == 0) dout[(size_t)kk*(NBATCH*ND) + (size_t)b*ND + tid] = v;
  }
  // W = L^{-1}: thread cc owns column cc, barrier-free forward substitution
  {
    int cc = tid;
    float* Wc = Wl + (size_t)cc*ND;
    for(int i = 0; i < ND; i++){
      if(cc <= i && cc < ND){
        float s = (i == cc) ? 1.f : 0.f;
        const float* Ar = A + (size_t)i*APITCH;
        #pragma unroll 4
        for(int k = cc; k < i; k++) s -= Ar[k]*Wc[k];
        Wc[i] = s * rs[i];
      }
    }
  }
  __syncthreads();
  // packed write: column e rows (e&~3)..131, zero-filled
  {
    float* dst0 = Wpk + (size_t)c*WPACK;
    int S = 0;
    for(int e = 0; e < 132; e++){
      int dstart = e & ~3;
      float* dst = dst0 + S;
      for(int i = dstart + tid; i < 132; i += 256){
        float v = 0.f;
        if(e < ND && i >= e && i < ND) v = Wl[(size_t)e*ND + i];
        dst[i - dstart] = v;
      }
      S += 132 - dstart;
    }
  }
}

// ---------------- quad = || W (z - mu) ||^2 per pixel ----------------
// v3: DF-only in LDS (35.9 KB -> 4 blocks/CU); W read directly from global
// (wave-coalesced float4, L2-hot); incremental packed-base addressing.
// Thread tile = 4 rows x 4 pixels, 2 d-sweeps; (P==1, ty==15) fat tile covers
// rows 128..131 (B quads); tail loop handles column e=128 B-quad-only.

#define QFMA(acc, wv) \
  acc.x += (wv)*x.x; acc.y += (wv)*x.y; acc.z += (wv)*x.z; acc.w += (wv)*x.w;

__global__ __launch_bounds__(256) void k_quad(const float* fgbg, const float* cfcb, const float* qf,
                                              const float* Wp, const float* mu, float* quad){
  extern __shared__ float sh[];
  float* DF = sh;             // [132][68]
  int c = blockIdx.y;
  int br = c >> 5, b = (c >> 2) & 7;
  int n0 = blockIdx.x*64;
  int tid = threadIdx.x;
  // stage DF = z - mu (pad rows 129..131 = 0)
  for(int idx = tid; idx < 132*16; idx += 256){
    int r = idx >> 4, c4 = (idx & 15)*4;
    float4 v = make_float4(0.f, 0.f, 0.f, 0.f);
    if(r < ND){
      const float* Zr = zrow(fgbg, cfcb, qf, br, b, r);
      v = *(const float4*)(Zr + n0 + c4);
      float m = mu[(size_t)c*ND + r];
      v.x -= m; v.y -= m; v.z -= m; v.w -= m;
    }
    *(float4*)&DF[r*68 + c4] = v;
  }
  __syncthreads();
  const float4* Wc4 = (const float4*)(Wp + (size_t)c*WPACK);
  int tx = tid & 15, ty = tid >> 4;
  int p0 = 4*tx;
  float4 q = make_float4(0.f, 0.f, 0.f, 0.f);
  #pragma unroll
  for(int P = 0; P < 2; P++){
    int d0 = 4*(16*P + ty);
    bool fat = (P == 1) && (ty == 15);
    int eA = min(d0 + 4, ND);
    float4 A0 = make_float4(0,0,0,0), A1 = A0, A2 = A0, A3 = A0;
    float4 B0 = A0, B1 = A0, B2 = A0, B3 = A0;
    // base4 = (S(e) + d0 - 4*(e>>2)) / 4, maintained incrementally:
    // delta = 33 - (e>>2) - ((e&3)==3)
    int base4 = d0 >> 2;
    #pragma unroll 4
    for(int e = 0; e < eA; e++){
      float4 x = *(const float4*)&DF[e*68 + p0];
      float4 w = Wc4[base4];
      QFMA(A0, w.x) QFMA(A1, w.y) QFMA(A2, w.z) QFMA(A3, w.w)
      if(fat){
        float4 w2 = Wc4[base4 + 1];
        QFMA(B0, w2.x) QFMA(B1, w2.y) QFMA(B2, w2.z) QFMA(B3, w2.w)
      }
      base4 += 33 - (e >> 2) - (((e & 3) == 3) ? 1 : 0);
    }
    if(fat){
      base4 += 1;                       // fat tail rows start at d0+4
      for(int e = eA; e < ND; e++){     // e == 128 only (dstart == 128)
        float4 x = *(const float4*)&DF[e*68 + p0];
        float4 w2 = Wc4[base4];
        QFMA(B0, w2.x) QFMA(B1, w2.y) QFMA(B2, w2.z) QFMA(B3, w2.w)
        base4 += 33 - (e >> 2) - (((e & 3) == 3) ? 1 : 0);
      }
    }
    q.x += A0.x*A0.x + A1.x*A1.x + A2.x*A2.x + A3.x*A3.x;
    q.y += A0.y*A0.y + A1.y*A1.y + A2.y*A2.y + A3.y*A3.y;
    q.z += A0.z*A0.z + A1.z*A1.z + A2.z*A2.z + A3.z*A3.z;
    q.w += A0.w*A0.w + A1.w*A1.w + A2.w*A2.w + A3.w*A3.w;
    if(fat){
      q.x += B0.x*B0.x + B1.x*B1.x + B2.x*B2.x + B3.x*B3.x;
      q.y += B0.y*B0.y + B1.y*B1.y + B2.y*B2.y + B3.y*B3.y;
      q.z += B0.z*B0.z + B1.z*B1.z + B2.z*B2.z + B3.z*B3.z;
      q.w += B0.w*B0.w + B1.w*B1.w + B2.w*B2.w + B3.w*B3.w;
    }
  }
  __syncthreads();                     // all DF reads complete -> reuse as QR
  float* QR = sh;                      // [16][68]
  *(float4*)&QR[ty*68 + p0] = q;
  __syncthreads();
  if(tid < 64){
    float s = 0.f;
    #pragma unroll
    for(int t = 0; t < 16; t++) s += QR[t*68 + tid];
    quad[(size_t)c*NPIX + n0 + tid] = s;
  }
}

// ---------------- energy ----------------

__global__ __launch_bounds__(256) void k_energy(const float* quad, const float* logdet, const float* logphi,
                                                float* eacc){
  __shared__ float rb[256];
  int tid = threadIdx.x;
  int n = blockIdx.x*256 + tid, b = blockIdx.y, br = blockIdx.z;
  int c0 = (br*NBATCH + b)*NK;
  const float C0 = 118.54307078340277f;  // 0.5 * 129 * ln(2*pi)
  float l0 = -0.5f*quad[(size_t)(c0 + 0)*NPIX + n] - 0.5f*logdet[c0 + 0] - C0 + logphi[c0 + 0];
  float l1 = -0.5f*quad[(size_t)(c0 + 1)*NPIX + n] - 0.5f*logdet[c0 + 1] - C0 + logphi[c0 + 1];
  float l2 = -0.5f*quad[(size_t)(c0 + 2)*NPIX + n] - 0.5f*logdet[c0 + 2] - C0 + logphi[c0 + 2];
  float l3 = -0.5f*quad[(size_t)(c0 + 3)*NPIX + n] - 0.5f*logdet[c0 + 3] - C0 + logphi[c0 + 3];
  float mx = fmaxf(fmaxf(l0, l1), fmaxf(l2, l3));
  float lse = mx + logf(expf(l0 - mx) + expf(l1 - mx) + expf(l2 - mx) + expf(l3 - mx));
  float t = blockSum256(lse, rb);
  if(tid == 0) atomicAdd(&eacc[br], t);
}

__global__ void k_fin(const float* eacc, float* dout){
  int t = threadIdx.x;
  if(t < 2) dout[151584 + t] = -eacc[t] / (float)(NBATCH*NPIX);
}

// ---------------- discriminative prob map ----------------

__global__ __launch_bounds__(256) void k_prob(const float* fgbg, const float* cfcb, const float* qf,
                                              const float* fs, float* dout){
  __shared__ float MC[8][132];
  int b = blockIdx.y, tid = threadIdx.x;
  for(int idx = tid; idx < 8*ND; idx += 256){
    int m = idx / ND, d = idx - m*ND;
    int br = m >> 2, kk = m & 3;
    MC[m][d] = fs[(size_t)((br*NBATCH + b)*NK + kk)*ND + d];
  }
  __syncthreads();
  int n = blockIdx.x*256 + tid;
  float a[8] = {0,0,0,0,0,0,0,0};
  const float* Z0 = fgbg + ((size_t)(b*NC))*NPIX + n;
  for(int d = 0; d < NC; d++){
    float z = Z0[(size_t)d*NPIX];
    #pragma unroll
    for(int m = 0; m < 8; m++) a[m] += z*MC[m][d];
  }
  const float* Q = qf + ((size_t)(b*NC))*NPIX + n;
  for(int d = 0; d < NC; d++){
    float z = Q[(size_t)d*NPIX];
    #pragma unroll
    for(int m = 0; m < 8; m++) a[m] += z*MC[m][NC + d];
  }
  {
    float z = cfcb[(size_t)b*NPIX + n];
    #pragma unroll
    for(int m = 0; m < 8; m++) a[m] += z*MC[m][128];
  }
  float mx = a[0];
  #pragma unroll
  for(int m = 1; m < 8; m++) mx = fmaxf(mx, a[m]);
  float e[8]; float ssum = 0.f;
  #pragma unroll
  for(int m = 0; m < 8; m++){ e[m] = expf(a[m] - mx); ssum += e[m]; }
  float inv = 1.f/ssum;
  float Pf = (e[0] + e[1] + e[2] + e[3])*inv;
  float Pb = (e[4] + e[5] + e[6] + e[7])*inv;
  dout[4128 + ((size_t)(b*2))*NPIX + n]     = Pb;
  dout[4128 + ((size_t)(b*2 + 1))*NPIX + n] = Pf;
}

// ---------------- launcher ----------------

extern "C" void kernel_launch(void* const* d_in, const int* in_sizes, int n_in,
                              void* d_out, int out_size, void* d_ws, size_t ws_size,
                              hipStream_t stream){
  const float* sf  = (const float*)d_in[0];
  const float* smk = (const float*)d_in[1];
  const float* qfp = (const float*)d_in[2];
  const float* w1  = (const float*)d_in[3];
  const float* b1  = (const float*)d_in[4];
  const float* g1  = (const float*)d_in[5];
  const float* be1 = (const float*)d_in[6];
  const float* w2  = (const float*)d_in[7];
  const float* b2  = (const float*)d_in[8];
  const float* g2  = (const float*)d_in[9];
  const float* be2 = (const float*)d_in[10];
  const float* w3  = (const float*)d_in[11];
  const float* b3  = (const float*)d_in[12];
  const float* nzf = (const float*)d_in[13];
  const float* nzb = (const float*)d_in[14];
  float* out = (float*)d_out;
  float* W   = (float*)d_ws;

  constexpr size_t OFF_FGBG  = 0;
  constexpr size_t SZ_FGBG   = (size_t)2*NBATCH*NC*NPIX;
  constexpr size_t OFF_CFCB  = OFF_FGBG + SZ_FGBG;
  constexpr size_t SZ_CFCB   = (size_t)2*NBATCH*NPIX;
  constexpr size_t OFF_H1    = OFF_CFCB + SZ_CFCB;
  constexpr size_t SZ_H1     = (size_t)2*NBATCH*NC*NPIX;
  constexpr size_t OFF_MPART = OFF_H1;
  constexpr size_t SZ_MPART  = (size_t)4*NCOMBO*ND*PITCH;
  constexpr size_t OFF_COVB  = OFF_H1 + SZ_MPART;
  constexpr size_t OFF_H2    = OFF_H1 + SZ_H1;
  constexpr size_t SZ_H2     = (size_t)2*NBATCH*16*NPIX;
  constexpr size_t OFF_W     = OFF_H2;              // packed W^-1 reuses h2
  constexpr size_t OFF_GAMMA = OFF_H2 + SZ_H2;
  constexpr size_t SZ_GAMMA  = (size_t)2*NBATCH*NK*NPIX;
  constexpr size_t OFF_QUAD  = OFF_GAMMA + SZ_GAMMA;
  constexpr size_t SZ_QUAD   = SZ_GAMMA;
  constexpr size_t OFF_SC    = OFF_QUAD + SZ_QUAD;

  float* fgbg  = W + OFF_FGBG;
  float* cfcb  = W + OFF_CFCB;
  float* h1    = W + OFF_H1;
  float* h2    = W + OFF_H2;
  float* gamma = W + OFF_GAMMA;
  float* quad  = W + OFF_QUAD;
  float* Mpart = W + OFF_MPART;
  float* covb  = W + OFF_COVB;
  float* Wpack = W + OFF_W;
  float* sc    = W + OFF_SC;
  float* mean1 = sc;          float* rstd1  = sc + 128;
  float* mean2 = sc + 256;    float* rstd2  = sc + 288;
  float* sumg  = sc + 320;    float* eacc   = sc + 384;   // zero region: sumg..bnp2 (386 floats)
  float* bnp1  = sc + 386;    float* bnp2   = sc + 642;
  float* phi   = sc + 706;    float* logphi = sc + 770;
  float* mu    = sc + 834;
  float* logdetv = sc + 9090;
  float* fsv   = sc + 9154;

  hipMemsetAsync(sumg, 0, 386*sizeof(float), stream);

  k_prep   <<<dim3(36, 8),      256, 0, stream>>>(sf, smk, qfp, fgbg, cfcb);
  k_conv1  <<<dim3(36, 8, 2),   256, 0, stream>>>(fgbg, cfcb, qfp, w1, b1, h1);
  k_bnpart <<<dim3(64, 2, 8),   256, 0, stream>>>(h1, bnp1, 64);
  k_bnfin  <<<2, 64,                0, stream>>>(bnp1, mean1, rstd1, 64);
  k_conv2  <<<dim3(36, 8, 2),   256, 0, stream>>>(h1, mean1, rstd1, g1, be1, w2, b2, h2);
  k_bnpart <<<dim3(16, 2, 8),   256, 0, stream>>>(h2, bnp2, 16);
  k_bnfin  <<<1, 64,                0, stream>>>(bnp2, mean2, rstd2, 16);
  k_gamma  <<<dim3(36, 8, 2),   256, 0, stream>>>(h2, mean2, rstd2, g2, be2, w3, b3, gamma, sumg);
  k_musum  <<<dim3(129, 8, 2),  256, 0, stream>>>(fgbg, cfcb, qfp, gamma, mu);
  k_phimufin<<<1,               256, 0, stream>>>(sumg, phi, logphi, mu);
  k_cov    <<<dim3(10, 16, 4),  256, 0, stream>>>(fgbg, cfcb, qfp, gamma, Mpart);
  k_covstrip<<<dim3(129, 16, 4),256, 0, stream>>>(fgbg, cfcb, qfp, gamma, Mpart);
  k_covfin <<<dim3(129, 64),    192, 0, stream>>>(Mpart, sumg, mu, covb);
  k_cholinv<<<64, 256, (ND*APITCH + ND*ND + 132 + 4)*sizeof(float), stream>>>(covb, mu, phi, nzf, nzb,
                                                                              Wpack, logdetv, fsv, out);
  k_quad   <<<dim3(144, 64),    256, (132*68)*sizeof(float), stream>>>(
                                     fgbg, cfcb, qfp, Wpack, mu, quad);
  k_energy <<<dim3(36, 8, 2),   256, 0, stream>>>(quad, logdetv, logphi, eacc);
  k_prob   <<<dim3(36, 8),      256, 0, stream>>>(fgbg, cfcb, qfp, fsv, out);
  k_fin    <<<1, 64, 0, stream>>>(eacc, out);
}

// Round 9
// 1241.434 us; speedup vs baseline: 1.6207x; 1.1231x over previous
//
#include <hip/hip_runtime.h>
#include <math.h>

#define NPIX 9216
#define NBATCH 8
#define NC 64
#define ND 129
#define NK 4
#define NCOMBO 64   // 2 branches * 8 batch * 4 k
#define PITCH 132   // row pitch for 129-wide matrices in global
#define CAP 132     // cholinv A row pitch: rows 16B-aligned; quad stride 33 ≡ 1 mod 8 -> b128 conflict-free
#define CWP 130     // cholinv Wl column pitch: lane stride 131 ≡ 3 mod 32 -> conflict-free
#define WPACK 8976  // packed triangular W floats per combo (4-aligned columns)

// ---------------- helpers ----------------

__device__ __forceinline__ const float* zrow(const float* fgbg, const float* cfcb, const float* qf,
                                             int br, int b, int d){
  if(d < NC)        return fgbg + ((size_t)((br*NBATCH + b)*NC + d))*NPIX;
  else if(d < 2*NC) return qf   + ((size_t)(b*NC + (d - NC)))*NPIX;
  else              return cfcb + (size_t)(br*NBATCH + b)*NPIX;
}

__device__ __forceinline__ float blockSum256(float v, float* rb){
  int tid = threadIdx.x;
  rb[tid] = v; __syncthreads();
  #pragma unroll
  for(int s = 128; s > 0; s >>= 1){
    if(tid < s) rb[tid] += rb[tid + s];
    __syncthreads();
  }
  float r = rb[0]; __syncthreads();
  return r;
}

// ---------------- stage 1: fg/bg/cosine ----------------

__global__ __launch_bounds__(256) void k_prep(const float* sf, const float* smk, const float* qf,
                                              float* fgbg, float* cfcb){
  int tid = threadIdx.x, b = blockIdx.y;
  int n = blockIdx.x*256 + tid;
  float m = smk[(size_t)b*NPIX + n];
  const float* S = sf + ((size_t)(b*NC))*NPIX + n;
  const float* Q = qf + ((size_t)(b*NC))*NPIX + n;
  float* FG = fgbg + ((size_t)(b*NC))*NPIX + n;
  float* BG = fgbg + ((size_t)((NBATCH + b)*NC))*NPIX + n;
  float df = 0.f, db = 0.f, nf = 0.f, nb_ = 0.f, nq = 0.f;
  #pragma unroll 4
  for(int c = 0; c < NC; c++){
    float s = S[(size_t)c*NPIX], q = Q[(size_t)c*NPIX];
    float f = s*m, g = s - f;
    FG[(size_t)c*NPIX] = f; BG[(size_t)c*NPIX] = g;
    df += f*q; db += g*q; nf += f*f; nb_ += g*g; nq += q*q;
  }
  float rq = fmaxf(sqrtf(nq), 1e-8f);
  cfcb[(size_t)b*NPIX + n]            = df / (fmaxf(sqrtf(nf),  1e-8f) * rq);
  cfcb[(size_t)(NBATCH + b)*NPIX + n] = db / (fmaxf(sqrtf(nb_), 1e-8f) * rq);
}

// ---------------- estimator ----------------

__global__ __launch_bounds__(256) void k_conv1(const float* fgbg, const float* cfcb, const float* qf,
                                               const float* w1, const float* b1, float* h1){
  __shared__ float Ws[ND*NC];
  __shared__ float B1[NC];
  int tid = threadIdx.x, b = blockIdx.y, br = blockIdx.z;
  for(int i = tid; i < ND*NC; i += 256) Ws[i] = w1[i];
  if(tid < NC) B1[tid] = b1[tid];
  __syncthreads();
  int n = blockIdx.x*256 + tid;
  float acc[NC];
  #pragma unroll
  for(int j = 0; j < NC; j++) acc[j] = B1[j];
  const float* Z0 = fgbg + ((size_t)((br*NBATCH + b)*NC))*NPIX + n;
  #pragma unroll 2
  for(int d = 0; d < NC; d++){
    float z = Z0[(size_t)d*NPIX];
    #pragma unroll
    for(int j = 0; j < NC; j++) acc[j] += z*Ws[d*NC + j];
  }
  const float* Q = qf + ((size_t)(b*NC))*NPIX + n;
  #pragma unroll 2
  for(int d = 0; d < NC; d++){
    float z = Q[(size_t)d*NPIX];
    #pragma unroll
    for(int j = 0; j < NC; j++) acc[j] += z*Ws[(NC + d)*NC + j];
  }
  {
    float z = cfcb[(size_t)(br*NBATCH + b)*NPIX + n];
    #pragma unroll
    for(int j = 0; j < NC; j++) acc[j] += z*Ws[128*NC + j];
  }
  float* O = h1 + ((size_t)((br*NBATCH + b)*NC))*NPIX + n;
  #pragma unroll
  for(int j = 0; j < NC; j++) O[(size_t)j*NPIX] = acc[j];
}

// BN batch-stats: parallel partial sums + atomics, then tiny finalize
__global__ __launch_bounds__(256) void k_bnpart(const float* x, float* part, int C){
  __shared__ float rb[256];
  int c = blockIdx.x, br = blockIdx.y, b = blockIdx.z, tid = threadIdx.x;
  const float4* X = (const float4*)(x + ((size_t)((br*NBATCH + b)*C + c))*NPIX);
  float s = 0.f, ss = 0.f;
  for(int n = tid; n < NPIX/4; n += 256){
    float4 v = X[n];
    s  += v.x + v.y + v.z + v.w;
    ss += v.x*v.x + v.y*v.y + v.z*v.z + v.w*v.w;
  }
  float S  = blockSum256(s,  rb);
  float SS = blockSum256(ss, rb);
  if(tid == 0){
    atomicAdd(&part[(size_t)(br*C + c)*2],     S);
    atomicAdd(&part[(size_t)(br*C + c)*2 + 1], SS);
  }
}

__global__ void k_bnfin(const float* part, float* meanv, float* rstdv, int C){
  int i = blockIdx.x*64 + threadIdx.x;
  if(i < 2*C){
    float m = part[(size_t)i*2]     / (float)(NBATCH*NPIX);
    float v = part[(size_t)i*2 + 1] / (float)(NBATCH*NPIX) - m*m;
    meanv[i] = m;
    rstdv[i] = 1.0f / sqrtf(v + 1e-5f);
  }
}

__global__ __launch_bounds__(256) void k_conv2(const float* h1, const float* mean1, const float* rstd1,
                                               const float* g1, const float* be1,
                                               const float* w2, const float* b2, float* h2){
  __shared__ float Ws[NC*16];
  __shared__ float Pm[NC], Pr[NC], Pg[NC], Pb[NC];
  __shared__ float B2[16];
  int tid = threadIdx.x, b = blockIdx.y, br = blockIdx.z;
  for(int i = tid; i < NC*16; i += 256) Ws[i] = w2[i];
  if(tid < NC){ Pm[tid] = mean1[br*NC + tid]; Pr[tid] = rstd1[br*NC + tid]; Pg[tid] = g1[tid]; Pb[tid] = be1[tid]; }
  if(tid < 16) B2[tid] = b2[tid];
  __syncthreads();
  int n = blockIdx.x*256 + tid;
  const float* X = h1 + ((size_t)((br*NBATCH + b)*NC))*NPIX + n;
  float acc[16];
  #pragma unroll
  for(int j = 0; j < 16; j++) acc[j] = B2[j];
  for(int c = 0; c < NC; c++){
    float v = (X[(size_t)c*NPIX] - Pm[c])*Pr[c]*Pg[c] + Pb[c];
    v = fmaxf(v, 0.f);
    #pragma unroll
    for(int j = 0; j < 16; j++) acc[j] += v*Ws[c*16 + j];
  }
  float* O = h2 + ((size_t)((br*NBATCH + b)*16))*NPIX + n;
  #pragma unroll
  for(int j = 0; j < 16; j++) O[(size_t)j*NPIX] = acc[j];
}

__global__ __launch_bounds__(256) void k_gamma(const float* h2, const float* mean2, const float* rstd2,
                                               const float* g2, const float* be2,
                                               const float* w3, const float* b3,
                                               float* gamma, float* sumg){
  __shared__ float W3[16*4];
  __shared__ float Pm[16], Pr[16], Pg[16], Pb[16];
  __shared__ float B3[4];
  __shared__ float rb[256];
  int tid = threadIdx.x, b = blockIdx.y, br = blockIdx.z;
  if(tid < 64) W3[tid] = w3[tid];
  if(tid < 4)  B3[tid] = b3[tid];
  if(tid < 16){ Pm[tid] = mean2[br*16 + tid]; Pr[tid] = rstd2[br*16 + tid]; Pg[tid] = g2[tid]; Pb[tid] = be2[tid]; }
  __syncthreads();
  int n = blockIdx.x*256 + tid;
  const float* X = h2 + ((size_t)((br*NBATCH + b)*16))*NPIX + n;
  float l0 = B3[0], l1 = B3[1], l2 = B3[2], l3 = B3[3];
  #pragma unroll
  for(int c = 0; c < 16; c++){
    float v = (X[(size_t)c*NPIX] - Pm[c])*Pr[c]*Pg[c] + Pb[c];
    v = fmaxf(v, 0.f);
    l0 += v*W3[c*4 + 0]; l1 += v*W3[c*4 + 1]; l2 += v*W3[c*4 + 2]; l3 += v*W3[c*4 + 3];
  }
  float mx = fmaxf(fmaxf(l0, l1), fmaxf(l2, l3));
  float e0 = expf(l0 - mx), e1 = expf(l1 - mx), e2 = expf(l2 - mx), e3 = expf(l3 - mx);
  float inv = 1.0f / (e0 + e1 + e2 + e3);
  float q0 = e0*inv, q1 = e1*inv, q2 = e2*inv, q3 = e3*inv;
  float* G = gamma + ((size_t)((br*NBATCH + b)*NK))*NPIX + n;
  G[0] = q0; G[NPIX] = q1; G[2*NPIX] = q2; G[3*NPIX] = q3;
  int cb = br*NBATCH + b;
  float t;
  t = blockSum256(q0, rb); if(tid == 0) atomicAdd(&sumg[cb*4 + 0], t);
  t = blockSum256(q1, rb); if(tid == 0) atomicAdd(&sumg[cb*4 + 1], t);
  t = blockSum256(q2, rb); if(tid == 0) atomicAdd(&sumg[cb*4 + 2], t);
  t = blockSum256(q3, rb); if(tid == 0) atomicAdd(&sumg[cb*4 + 3], t);
}

// ---------------- GMM: mu ----------------

__global__ __launch_bounds__(256) void k_musum(const float* fgbg, const float* cfcb, const float* qf,
                                               const float* gamma, float* musum){
  __shared__ float rb[256];
  int d = blockIdx.x, b = blockIdx.y, br = blockIdx.z, tid = threadIdx.x;
  const float* Z = zrow(fgbg, cfcb, qf, br, b, d);
  const float* G = gamma + ((size_t)((br*NBATCH + b)*NK))*NPIX;
  float a0 = 0.f, a1 = 0.f, a2 = 0.f, a3 = 0.f;
  for(int n = tid; n < NPIX; n += 256){
    float z = Z[n];
    a0 += G[n]*z; a1 += G[NPIX + n]*z; a2 += G[2*NPIX + n]*z; a3 += G[3*NPIX + n]*z;
  }
  int cb = br*NBATCH + b;
  float t;
  t = blockSum256(a0, rb); if(tid == 0) musum[((size_t)(cb*4 + 0))*ND + d] = t;
  t = blockSum256(a1, rb); if(tid == 0) musum[((size_t)(cb*4 + 1))*ND + d] = t;
  t = blockSum256(a2, rb); if(tid == 0) musum[((size_t)(cb*4 + 2))*ND + d] = t;
  t = blockSum256(a3, rb); if(tid == 0) musum[((size_t)(cb*4 + 3))*ND + d] = t;
}

__global__ __launch_bounds__(256) void k_phimufin(const float* sumg, float* phi, float* logphi, float* mu){
  int tid = threadIdx.x;
  if(tid < NCOMBO){
    float sg = sumg[tid];
    float p = sg / (float)NPIX;
    phi[tid] = p;
    logphi[tid] = logf(p + 1e-12f);
  }
  for(int i = tid; i < NCOMBO*ND; i += 256){
    int c = i / ND;
    mu[i] = mu[i] / sumg[c];
  }
}

// ---------------- GMM: weighted second moment (upper triangle, tiles of 32) ----------------

__global__ __launch_bounds__(256) void k_cov(const float* fgbg, const float* cfcb, const float* qf,
                                             const float* gamma, float* Mpart){
  __shared__ float SD[32][34];
  __shared__ float SE[32][34];
  __shared__ __align__(16) float SG[32][4];
  int p = blockIdx.x, cbi = blockIdx.y, seg = blockIdx.z;
  int ti, tj;
  if(p < 4){ ti = 0; tj = p; } else if(p < 7){ ti = 1; tj = p - 3; }
  else if(p < 9){ ti = 2; tj = p - 5; } else { ti = 3; tj = 3; }
  int br = cbi >> 3, b = cbi & 7;
  int d0 = ti*32, e0 = tj*32;
  int tid = threadIdx.x, tx = tid & 15, ty = tid >> 4;
  float at[2][2] = {{0,0},{0,0}}, a0[2][2] = {{0,0},{0,0}}, a1[2][2] = {{0,0},{0,0}}, a2[2][2] = {{0,0},{0,0}};
  const float* G = gamma + ((size_t)(cbi*NK))*NPIX;
  int r = tid >> 3, jj = (tid & 7)*4;
  const float* Zd = zrow(fgbg, cfcb, qf, br, b, d0 + r);
  const float* Ze = zrow(fgbg, cfcb, qf, br, b, e0 + r);
  for(int nc = 0; nc < 72; nc++){
    int n0 = seg*2304 + nc*32;
    __syncthreads();
    {
      float4 v = *(const float4*)(Zd + n0 + jj);
      SD[jj][r] = v.x; SD[jj+1][r] = v.y; SD[jj+2][r] = v.z; SD[jj+3][r] = v.w;
      v = *(const float4*)(Ze + n0 + jj);
      SE[jj][r] = v.x; SE[jj+1][r] = v.y; SE[jj+2][r] = v.z; SE[jj+3][r] = v.w;
      if(tid < 128) SG[tid & 31][tid >> 5] = G[(size_t)(tid >> 5)*NPIX + n0 + (tid & 31)];
    }
    __syncthreads();
    #pragma unroll 4
    for(int nn = 0; nn < 32; nn++){
      float4 g4 = *(const float4*)(&SG[nn][0]);
      float zd0 = SD[nn][2*ty], zd1 = SD[nn][2*ty + 1];
      float ze0 = SE[nn][2*tx], ze1 = SE[nn][2*tx + 1];
      #pragma unroll
      for(int i = 0; i < 2; i++){
        float zd = i ? zd1 : zd0;
        #pragma unroll
        for(int j = 0; j < 2; j++){
          float ze = j ? ze1 : ze0;
          float pr = zd*ze;
          at[i][j] += pr;
          a0[i][j] += g4.x*pr;
          a1[i][j] += g4.y*pr;
          a2[i][j] += g4.z*pr;
        }
      }
    }
  }
  size_t slot0 = (size_t)(seg*64 + cbi*4);
  size_t st = (size_t)ND*PITCH;
  #pragma unroll
  for(int i = 0; i < 2; i++){
    #pragma unroll
    for(int j = 0; j < 2; j++){
      int d = d0 + 2*ty + i, e = e0 + 2*tx + j;
      if(e >= d){
        size_t o = (slot0*ND + d)*PITCH + e;
        Mpart[o]        = a0[i][j];
        Mpart[o + st]   = a1[i][j];
        Mpart[o + 2*st] = a2[i][j];
        Mpart[o + 3*st] = at[i][j];
      }
    }
  }
}

__global__ __launch_bounds__(256) void k_covstrip(const float* fgbg, const float* cfcb, const float* qf,
                                                  const float* gamma, float* Mpart){
  __shared__ float rb[256];
  int e = blockIdx.x, cb = blockIdx.y, seg = blockIdx.z, tid = threadIdx.x;
  int br = cb >> 3, b = cb & 7;
  const float* Ze = zrow(fgbg, cfcb, qf, br, b, e);
  const float* CF = cfcb + (size_t)cb*NPIX;
  const float* G  = gamma + ((size_t)(cb*NK))*NPIX;
  float at = 0.f, a0 = 0.f, a1 = 0.f, a2 = 0.f;
  int n0 = seg*2304;
  for(int n = n0 + tid; n < n0 + 2304; n += 256){
    float pr = Ze[n]*CF[n];
    at += pr; a0 += G[n]*pr; a1 += G[NPIX + n]*pr; a2 += G[2*NPIX + n]*pr;
  }
  size_t base = ((size_t)(seg*64 + cb*4)*ND + e)*PITCH + 128;
  size_t st = (size_t)ND*PITCH;
  float t;
  t = blockSum256(a0, rb); if(tid == 0) Mpart[base]        = t;
  t = blockSum256(a1, rb); if(tid == 0) Mpart[base + st]   = t;
  t = blockSum256(a2, rb); if(tid == 0) Mpart[base + 2*st] = t;
  t = blockSum256(at, rb); if(tid == 0) Mpart[base + 3*st] = t;
}

__global__ __launch_bounds__(192) void k_covfin(const float* Mpart, const float* sumg, const float* mu,
                                                float* covb){
  int i = blockIdx.x, c = blockIdx.y, j = threadIdx.x;
  if(j > i) return;
  int k = c & 3, cb4 = c & ~3;
  size_t st = (size_t)ND*PITCH;
  float s = 0.f;
  if(k < 3){
    #pragma unroll
    for(int sg = 0; sg < 4; sg++) s += Mpart[((size_t)(sg*64 + c)*ND + j)*PITCH + i];
  } else {
    #pragma unroll
    for(int sg = 0; sg < 4; sg++){
      size_t base = ((size_t)(sg*64 + cb4)*ND + j)*PITCH + i;
      s += Mpart[base + 3*st] - Mpart[base] - Mpart[base + st] - Mpart[base + 2*st];
    }
  }
  float sgv = sumg[c];
  float v = s/sgv - mu[(size_t)c*ND + i]*mu[(size_t)c*ND + j];
  if(i == j) v += 1e-6f;
  covb[((size_t)c*ND + i)*PITCH + j] = v;
}

// ---------------- Cholesky (blocked rank-4) + logdet + sample + packed L^-1 ----------------
// Raw-column (LDL-ish) right-looking factorization, BF=4 panels:
//   mini-steps l=0..2 finalize panel columns J..J+3 for all rows;
//   rank-4 trailing update via b128 read/write (1R+1W per 4 cols amortized).
// Pivot reciprocals pipelined in dbuf: [0..1] = inv0 (panel parity), [2..4] = inv1..inv3.
// A pitch CAP=132 (b128-clean, 16B-aligned rows); Wl pitch CWP=130 (conflict-free).

__global__ __launch_bounds__(256) void k_cholinv(const float* covb, const float* muv, const float* phiv,
                                                 const float* nzf, const float* nzb,
                                                 float* Wpk, float* logdet, float* fs, float* dout){
  extern __shared__ float sh[];
  float* A    = sh;                    // ND x CAP, lower triangle (raw V, then L)
  float* Wl   = sh + ND*CAP;           // column-major: Wl[cc*CWP + i]
  float* rs   = Wl + ND*CWP;           // 132: 1/L[j][j]
  float* dbuf = rs + 132;              // 8: pivot reciprocals
  __shared__ float rb[256];
  int c = blockIdx.x, tid = threadIdx.x;
  for(int idx = tid; idx < ND*ND; idx += 256){
    int i = idx / ND, j = idx - i*ND;
    if(j <= i) A[(size_t)i*CAP + j] = covb[((size_t)c*ND + i)*PITCH + j];
  }
  if(tid == 0) dbuf[0] = 1.0f / A[0];
  __syncthreads();
  // blocked factorization
  for(int J = 0; J < ND; J += 4){
    int pb = (J >> 2) & 1;
    // panel mini-steps l = 0..2: pivot j=J+l updates panel cols m=l+1..3 (all rows)
    #pragma unroll
    for(int l = 0; l < 3; l++){
      int j = J + l;
      int i = j + 1 + tid;
      if(j < ND && i < ND){
        float invd = (l == 0) ? dbuf[pb] : dbuf[1 + l];
        float f = A[(size_t)i*CAP + j] * invd;
        #pragma unroll
        for(int m = l + 1; m < 4; m++){
          if(J + m < ND && i >= J + m){
            float piv = A[(size_t)(J + m)*CAP + j];
            float nv = A[(size_t)i*CAP + (J + m)] - f*piv;
            A[(size_t)i*CAP + (J + m)] = nv;
            if(i == J + m && m == l + 1) dbuf[2 + l] = 1.0f / nv;  // inv_{l+1}
          }
        }
      }
      __syncthreads();
    }
    // rank-4 trailing update: rows i >= J+4, cols k = J+4..i (b128)
    {
      int i = J + 4 + tid;
      if(J + 4 < ND && i < ND){
        float i0 = dbuf[pb], i1 = dbuf[2], i2 = dbuf[3], i3 = dbuf[4];
        float* Ai = A + (size_t)i*CAP;
        float4 fv = *(const float4*)&Ai[J];
        float f0 = fv.x*i0, f1 = fv.y*i1, f2 = fv.z*i2, f3 = fv.w*i3;
        int k = J + 4;
        int nq = (i - k + 1) >> 2;
        for(int q = 0; q < nq; q++, k += 4){
          float4 x  = *(const float4*)&Ai[k];
          float4 c0 = *(const float4*)&A[(size_t)(k+0)*CAP + J];
          float4 c1 = *(const float4*)&A[(size_t)(k+1)*CAP + J];
          float4 c2 = *(const float4*)&A[(size_t)(k+2)*CAP + J];
          float4 c3 = *(const float4*)&A[(size_t)(k+3)*CAP + J];
          x.x -= f0*c0.x + f1*c0.y + f2*c0.z + f3*c0.w;
          x.y -= f0*c1.x + f1*c1.y + f2*c1.z + f3*c1.w;
          x.z -= f0*c2.x + f1*c2.y + f2*c2.z + f3*c2.w;
          x.w -= f0*c3.x + f1*c3.y + f2*c3.z + f3*c3.w;
          *(float4*)&Ai[k] = x;
        }
        float nv = 0.f;
        for(; k <= i; k++){
          float4 ck = *(const float4*)&A[(size_t)k*CAP + J];
          nv = Ai[k] - (f0*ck.x + f1*ck.y + f2*ck.z + f3*ck.w);
          Ai[k] = nv;
        }
        if(i == J + 4) dbuf[pb ^ 1] = 1.0f / nv;   // next panel's inv0 (row J+4 tail is exactly the diagonal)
      }
      __syncthreads();
    }
  }
  // column scaling: L[i][j] = V[i][j] * rsqrt(d_j)
  if(tid < ND) rs[tid] = 1.0f / sqrtf(A[(size_t)tid*CAP + tid]);
  __syncthreads();
  for(int idx = tid; idx < ND*ND; idx += 256){
    int i = idx / ND, j = idx - i*ND;
    if(j <= i) A[(size_t)i*CAP + j] *= rs[j];
  }
  __syncthreads();
  float ld = (tid < ND) ? logf(A[(size_t)tid*CAP + tid]) : 0.f;
  float lsum = blockSum256(ld, rb);
  if(tid == 0) logdet[c] = 2.f*lsum;
  int br = c >> 5, b = (c >> 2) & 7, kk = c & 3;
  const float* nz = (br ? nzb : nzf) + (size_t)(b*NK + kk)*ND;
  if(tid < ND){
    const float* Ar = A + (size_t)tid*CAP;
    float s = muv[(size_t)c*ND + tid];
    #pragma unroll 4
    for(int e = 0; e <= tid; e++) s += Ar[e]*nz[e];
    float v = s*phiv[c];
    fs[(size_t)c*ND + tid] = v;
    if(br == 0) dout[(size_t)kk*(NBATCH*ND) + (size_t)b*ND + tid] = v;
  }
  // W = L^{-1}: thread cc owns column cc, barrier-free forward substitution
  {
    int cc = tid;
    float* Wc = Wl + (size_t)cc*CWP;
    for(int i = 0; i < ND; i++){
      if(cc <= i && cc < ND){
        float s = (i == cc) ? 1.f : 0.f;
        const float* Ar = A + (size_t)i*CAP;
        #pragma unroll 4
        for(int k = cc; k < i; k++) s -= Ar[k]*Wc[k];
        Wc[i] = s * rs[i];
      }
    }
  }
  __syncthreads();
  // packed write: column e rows (e&~3)..131, zero-filled
  {
    float* dst0 = Wpk + (size_t)c*WPACK;
    int S = 0;
    for(int e = 0; e < 132; e++){
      int dstart = e & ~3;
      float* dst = dst0 + S;
      for(int i = dstart + tid; i < 132; i += 256){
        float v = 0.f;
        if(e < ND && i >= e && i < ND) v = Wl[(size_t)e*CWP + i];
        dst[i - dstart] = v;
      }
      S += 132 - dstart;
    }
  }
}

// ---------------- quad = || W (z - mu) ||^2 per pixel ----------------
// v3: DF-only in LDS (35.9 KB -> 4 blocks/CU); W read directly from global
// (wave-coalesced float4, L2-hot); incremental packed-base addressing.

#define QFMA(acc, wv) \
  acc.x += (wv)*x.x; acc.y += (wv)*x.y; acc.z += (wv)*x.z; acc.w += (wv)*x.w;

__global__ __launch_bounds__(256) void k_quad(const float* fgbg, const float* cfcb, const float* qf,
                                              const float* Wp, const float* mu, float* quad){
  extern __shared__ float sh[];
  float* DF = sh;             // [132][68]
  int c = blockIdx.y;
  int br = c >> 5, b = (c >> 2) & 7;
  int n0 = blockIdx.x*64;
  int tid = threadIdx.x;
  for(int idx = tid; idx < 132*16; idx += 256){
    int r = idx >> 4, c4 = (idx & 15)*4;
    float4 v = make_float4(0.f, 0.f, 0.f, 0.f);
    if(r < ND){
      const float* Zr = zrow(fgbg, cfcb, qf, br, b, r);
      v = *(const float4*)(Zr + n0 + c4);
      float m = mu[(size_t)c*ND + r];
      v.x -= m; v.y -= m; v.z -= m; v.w -= m;
    }
    *(float4*)&DF[r*68 + c4] = v;
  }
  __syncthreads();
  const float4* Wc4 = (const float4*)(Wp + (size_t)c*WPACK);
  int tx = tid & 15, ty = tid >> 4;
  int p0 = 4*tx;
  float4 q = make_float4(0.f, 0.f, 0.f, 0.f);
  #pragma unroll
  for(int P = 0; P < 2; P++){
    int d0 = 4*(16*P + ty);
    bool fat = (P == 1) && (ty == 15);
    int eA = min(d0 + 4, ND);
    float4 A0 = make_float4(0,0,0,0), A1 = A0, A2 = A0, A3 = A0;
    float4 B0 = A0, B1 = A0, B2 = A0, B3 = A0;
    int base4 = d0 >> 2;
    #pragma unroll 4
    for(int e = 0; e < eA; e++){
      float4 x = *(const float4*)&DF[e*68 + p0];
      float4 w = Wc4[base4];
      QFMA(A0, w.x) QFMA(A1, w.y) QFMA(A2, w.z) QFMA(A3, w.w)
      if(fat){
        float4 w2 = Wc4[base4 + 1];
        QFMA(B0, w2.x) QFMA(B1, w2.y) QFMA(B2, w2.z) QFMA(B3, w2.w)
      }
      base4 += 33 - (e >> 2) - (((e & 3) == 3) ? 1 : 0);
    }
    if(fat){
      base4 += 1;
      for(int e = eA; e < ND; e++){
        float4 x = *(const float4*)&DF[e*68 + p0];
        float4 w2 = Wc4[base4];
        QFMA(B0, w2.x) QFMA(B1, w2.y) QFMA(B2, w2.z) QFMA(B3, w2.w)
        base4 += 33 - (e >> 2) - (((e & 3) == 3) ? 1 : 0);
      }
    }
    q.x += A0.x*A0.x + A1.x*A1.x + A2.x*A2.x + A3.x*A3.x;
    q.y += A0.y*A0.y + A1.y*A1.y + A2.y*A2.y + A3.y*A3.y;
    q.z += A0.z*A0.z + A1.z*A1.z + A2.z*A2.z + A3.z*A3.z;
    q.w += A0.w*A0.w + A1.w*A1.w + A2.w*A2.w + A3.w*A3.w;
    if(fat){
      q.x += B0.x*B0.x + B1.x*B1.x + B2.x*B2.x + B3.x*B3.x;
      q.y += B0.y*B0.y + B1.y*B1.y + B2.y*B2.y + B3.y*B3.y;
      q.z += B0.z*B0.z + B1.z*B1.z + B2.z*B2.z + B3.z*B3.z;
      q.w += B0.w*B0.w + B1.w*B1.w + B2.w*B2.w + B3.w*B3.w;
    }
  }
  __syncthreads();
  float* QR = sh;
  *(float4*)&QR[ty*68 + p0] = q;
  __syncthreads();
  if(tid < 64){
    float s = 0.f;
    #pragma unroll
    for(int t = 0; t < 16; t++) s += QR[t*68 + tid];
    quad[(size_t)c*NPIX + n0 + tid] = s;
  }
}

// ---------------- energy ----------------

__global__ __launch_bounds__(256) void k_energy(const float* quad, const float* logdet, const float* logphi,
                                                float* eacc){
  __shared__ float rb[256];
  int tid = threadIdx.x;
  int n = blockIdx.x*256 + tid, b = blockIdx.y, br = blockIdx.z;
  int c0 = (br*NBATCH + b)*NK;
  const float C0 = 118.54307078340277f;  // 0.5 * 129 * ln(2*pi)
  float l0 = -0.5f*quad[(size_t)(c0 + 0)*NPIX + n] - 0.5f*logdet[c0 + 0] - C0 + logphi[c0 + 0];
  float l1 = -0.5f*quad[(size_t)(c0 + 1)*NPIX + n] - 0.5f*logdet[c0 + 1] - C0 + logphi[c0 + 1];
  float l2 = -0.5f*quad[(size_t)(c0 + 2)*NPIX + n] - 0.5f*logdet[c0 + 2] - C0 + logphi[c0 + 2];
  float l3 = -0.5f*quad[(size_t)(c0 + 3)*NPIX + n] - 0.5f*logdet[c0 + 3] - C0 + logphi[c0 + 3];
  float mx = fmaxf(fmaxf(l0, l1), fmaxf(l2, l3));
  float lse = mx + logf(expf(l0 - mx) + expf(l1 - mx) + expf(l2 - mx) + expf(l3 - mx));
  float t = blockSum256(lse, rb);
  if(tid == 0) atomicAdd(&eacc[br], t);
}

__global__ void k_fin(const float* eacc, float* dout){
  int t = threadIdx.x;
  if(t < 2) dout[151584 + t] = -eacc[t] / (float)(NBATCH*NPIX);
}

// ---------------- discriminative prob map ----------------

__global__ __launch_bounds__(256) void k_prob(const float* fgbg, const float* cfcb, const float* qf,
                                              const float* fs, float* dout){
  __shared__ float MC[8][132];
  int b = blockIdx.y, tid = threadIdx.x;
  for(int idx = tid; idx < 8*ND; idx += 256){
    int m = idx / ND, d = idx - m*ND;
    int br = m >> 2, kk = m & 3;
    MC[m][d] = fs[(size_t)((br*NBATCH + b)*NK + kk)*ND + d];
  }
  __syncthreads();
  int n = blockIdx.x*256 + tid;
  float a[8] = {0,0,0,0,0,0,0,0};
  const float* Z0 = fgbg + ((size_t)(b*NC))*NPIX + n;
  for(int d = 0; d < NC; d++){
    float z = Z0[(size_t)d*NPIX];
    #pragma unroll
    for(int m = 0; m < 8; m++) a[m] += z*MC[m][d];
  }
  const float* Q = qf + ((size_t)(b*NC))*NPIX + n;
  for(int d = 0; d < NC; d++){
    float z = Q[(size_t)d*NPIX];
    #pragma unroll
    for(int m = 0; m < 8; m++) a[m] += z*MC[m][NC + d];
  }
  {
    float z = cfcb[(size_t)b*NPIX + n];
    #pragma unroll
    for(int m = 0; m < 8; m++) a[m] += z*MC[m][128];
  }
  float mx = a[0];
  #pragma unroll
  for(int m = 1; m < 8; m++) mx = fmaxf(mx, a[m]);
  float e[8]; float ssum = 0.f;
  #pragma unroll
  for(int m = 0; m < 8; m++){ e[m] = expf(a[m] - mx); ssum += e[m]; }
  float inv = 1.f/ssum;
  float Pf = (e[0] + e[1] + e[2] + e[3])*inv;
  float Pb = (e[4] + e[5] + e[6] + e[7])*inv;
  dout[4128 + ((size_t)(b*2))*NPIX + n]     = Pb;
  dout[4128 + ((size_t)(b*2 + 1))*NPIX + n] = Pf;
}

// ---------------- launcher ----------------

extern "C" void kernel_launch(void* const* d_in, const int* in_sizes, int n_in,
                              void* d_out, int out_size, void* d_ws, size_t ws_size,
                              hipStream_t stream){
  const float* sf  = (const float*)d_in[0];
  const float* smk = (const float*)d_in[1];
  const float* qfp = (const float*)d_in[2];
  const float* w1  = (const float*)d_in[3];
  const float* b1  = (const float*)d_in[4];
  const float* g1  = (const float*)d_in[5];
  const float* be1 = (const float*)d_in[6];
  const float* w2  = (const float*)d_in[7];
  const float* b2  = (const float*)d_in[8];
  const float* g2  = (const float*)d_in[9];
  const float* be2 = (const float*)d_in[10];
  const float* w3  = (const float*)d_in[11];
  const float* b3  = (const float*)d_in[12];
  const float* nzf = (const float*)d_in[13];
  const float* nzb = (const float*)d_in[14];
  float* out = (float*)d_out;
  float* W   = (float*)d_ws;

  constexpr size_t OFF_FGBG  = 0;
  constexpr size_t SZ_FGBG   = (size_t)2*NBATCH*NC*NPIX;
  constexpr size_t OFF_CFCB  = OFF_FGBG + SZ_FGBG;
  constexpr size_t SZ_CFCB   = (size_t)2*NBATCH*NPIX;
  constexpr size_t OFF_H1    = OFF_CFCB + SZ_CFCB;
  constexpr size_t SZ_H1     = (size_t)2*NBATCH*NC*NPIX;
  constexpr size_t OFF_MPART = OFF_H1;
  constexpr size_t SZ_MPART  = (size_t)4*NCOMBO*ND*PITCH;
  constexpr size_t OFF_COVB  = OFF_H1 + SZ_MPART;
  constexpr size_t OFF_H2    = OFF_H1 + SZ_H1;
  constexpr size_t SZ_H2     = (size_t)2*NBATCH*16*NPIX;
  constexpr size_t OFF_W     = OFF_H2;              // packed W^-1 reuses h2
  constexpr size_t OFF_GAMMA = OFF_H2 + SZ_H2;
  constexpr size_t SZ_GAMMA  = (size_t)2*NBATCH*NK*NPIX;
  constexpr size_t OFF_QUAD  = OFF_GAMMA + SZ_GAMMA;
  constexpr size_t SZ_QUAD   = SZ_GAMMA;
  constexpr size_t OFF_SC    = OFF_QUAD + SZ_QUAD;

  float* fgbg  = W + OFF_FGBG;
  float* cfcb  = W + OFF_CFCB;
  float* h1    = W + OFF_H1;
  float* h2    = W + OFF_H2;
  float* gamma = W + OFF_GAMMA;
  float* quad  = W + OFF_QUAD;
  float* Mpart = W + OFF_MPART;
  float* covb  = W + OFF_COVB;
  float* Wpack = W + OFF_W;
  float* sc    = W + OFF_SC;
  float* mean1 = sc;          float* rstd1  = sc + 128;
  float* mean2 = sc + 256;    float* rstd2  = sc + 288;
  float* sumg  = sc + 320;    float* eacc   = sc + 384;   // zero region: sumg..bnp2 (386 floats)
  float* bnp1  = sc + 386;    float* bnp2   = sc + 642;
  float* phi   = sc + 706;    float* logphi = sc + 770;
  float* mu    = sc + 834;
  float* logdetv = sc + 9090;
  float* fsv   = sc + 9154;

  hipMemsetAsync(sumg, 0, 386*sizeof(float), stream);

  k_prep   <<<dim3(36, 8),      256, 0, stream>>>(sf, smk, qfp, fgbg, cfcb);
  k_conv1  <<<dim3(36, 8, 2),   256, 0, stream>>>(fgbg, cfcb, qfp, w1, b1, h1);
  k_bnpart <<<dim3(64, 2, 8),   256, 0, stream>>>(h1, bnp1, 64);
  k_bnfin  <<<2, 64,                0, stream>>>(bnp1, mean1, rstd1, 64);
  k_conv2  <<<dim3(36, 8, 2),   256, 0, stream>>>(h1, mean1, rstd1, g1, be1, w2, b2, h2);
  k_bnpart <<<dim3(16, 2, 8),   256, 0, stream>>>(h2, bnp2, 16);
  k_bnfin  <<<1, 64,                0, stream>>>(bnp2, mean2, rstd2, 16);
  k_gamma  <<<dim3(36, 8, 2),   256, 0, stream>>>(h2, mean2, rstd2, g2, be2, w3, b3, gamma, sumg);
  k_musum  <<<dim3(129, 8, 2),  256, 0, stream>>>(fgbg, cfcb, qfp, gamma, mu);
  k_phimufin<<<1,               256, 0, stream>>>(sumg, phi, logphi, mu);
  k_cov    <<<dim3(10, 16, 4),  256, 0, stream>>>(fgbg, cfcb, qfp, gamma, Mpart);
  k_covstrip<<<dim3(129, 16, 4),256, 0, stream>>>(fgbg, cfcb, qfp, gamma, Mpart);
  k_covfin <<<dim3(129, 64),    192, 0, stream>>>(Mpart, sumg, mu, covb);
  k_cholinv<<<64, 256, (ND*CAP + ND*CWP + 132 + 8)*sizeof(float), stream>>>(covb, mu, phi, nzf, nzb,
                                                                            Wpack, logdetv, fsv, out);
  k_quad   <<<dim3(144, 64),    256, (132*68)*sizeof(float), stream>>>(
                                     fgbg, cfcb, qfp, Wpack, mu, quad);
  k_energy <<<dim3(36, 8, 2),   256, 0, stream>>>(quad, logdetv, logphi, eacc);
  k_prob   <<<dim3(36, 8),      256, 0, stream>>>(fgbg, cfcb, qfp, fsv, out);
  k_fin    <<<1, 64, 0, stream>>>(eacc, out);
}